// Round 4
// baseline (352.148 us; speedup 1.0000x reference)
//
#include <hip/hip_runtime.h>
#include <stdint.h>

#define NM 2048

typedef _Float16 f16;
typedef __attribute__((ext_vector_type(8))) _Float16 half8;
typedef __attribute__((ext_vector_type(4))) float float4v;

// ---------------------------------------------------------------------------
// X = A - A^T  (f16).  |X| <~ 0.1 so f16 abs err < 4e-5/entry.
// ---------------------------------------------------------------------------
__global__ void skew_f16_kernel(const float* __restrict__ A, f16* __restrict__ X) {
    __shared__ float t[32][33];
    const int bx = blockIdx.x * 32, by = blockIdx.y * 32;
    const int tx = threadIdx.x, ty = threadIdx.y;
    #pragma unroll
    for (int r = 0; r < 32; r += 8)
        t[ty + r][tx] = A[(size_t)(bx + ty + r) * NM + by + tx];
    __syncthreads();
    #pragma unroll
    for (int r = 0; r < 32; r += 8) {
        const int i = by + ty + r, j = bx + tx;
        X[(size_t)i * NM + j] = (f16)(A[(size_t)i * NM + j] - t[tx][ty + r]);
    }
}

// ---------------------------------------------------------------------------
// 256x256-tile, BK=64, 8-wave 8-phase counted-vmcnt GEMM, split-K=4 ->
// 256 blocks (1/CU).  Round-4 changes vs round 3:
//  (1) sched_barrier(0) pins bound each MFMA cluster: asm "memory" clobbers
//      do NOT constrain register-only MFMA, so without pins the compiler
//      hoists the cluster above s_barrier/lgkmcnt(0), serializing phases
//      (rule #18).  Pins restore [reads|barrier|MFMA|barrier] regions.
//  (2) last-arriver ticket fusion: each block writes its f16 partial plane,
//      __threadfence() + agent-scope ACQ_REL fetch_add on a per-tile
//      counter; ticket==3 block reduces its tile in-kernel (no reduce
//      kernels, no spinning -> deadlock-impossible).
// Certification (round-3 discipline, unchanged): per-tile vmcnt(4) at end
// of p4 between lgkmcnt(0) and the closing barrier; tile reads only after
// {every wave's own vmcnt wait} -> barrier.
// LDS: 2 x 64 KB buffers = 128 KB, 1 block/CU, 2 waves/SIMD.
// ---------------------------------------------------------------------------
#define BARRIER asm volatile("s_barrier" ::: "memory")
#define LG0     asm volatile("s_waitcnt lgkmcnt(0)" ::: "memory")
#define W4      asm volatile("s_waitcnt vmcnt(4)" ::: "memory")
#define W0      asm volatile("s_waitcnt vmcnt(0)" ::: "memory")
#define SCHED0  __builtin_amdgcn_sched_barrier(0)
#define NOST    ((void)0)

#define STAGE_U(u, dst)                                                       \
    do {                                                                      \
        __builtin_amdgcn_global_load_lds(                                     \
            (const __attribute__((address_space(1))) void*)gsrc[u],           \
            (__attribute__((address_space(3))) void*)(uintptr_t)((dst) + loff[u]), \
            16, 0, 0);                                                        \
        __builtin_amdgcn_global_load_lds(                                     \
            (const __attribute__((address_space(1))) void*)(gsrc[u] + (size_t)128 * NM), \
            (__attribute__((address_space(3))) void*)(uintptr_t)((dst) + loff[u] + 8192), \
            16, 0, 0);                                                        \
        gsrc[u] += 64;                                                        \
    } while (0)

#define RD_A(BB, HOFF)                                                        \
    { _Pragma("unroll")                                                       \
      for (int r_ = 0; r_ < 4; ++r_)                                          \
        _Pragma("unroll")                                                     \
        for (int k_ = 0; k_ < 2; ++k_)                                        \
            ah[r_][k_] = *(const half8*)&(BB)[offA[r_][k_] + (HOFF)]; }

#define RD_B(BB, HOFF)                                                        \
    { _Pragma("unroll")                                                       \
      for (int c_ = 0; c_ < 2; ++c_)                                          \
        _Pragma("unroll")                                                     \
        for (int k_ = 0; k_ < 2; ++k_)                                        \
            bh[c_][k_] = *(const half8*)&(BB)[offB[c_][k_] + (HOFF)]; }

#define MQ(MH, NH)                                                            \
    __builtin_amdgcn_s_setprio(1);                                            \
    _Pragma("unroll")                                                         \
    for (int r_ = 0; r_ < 4; ++r_)                                            \
        _Pragma("unroll")                                                     \
        for (int c_ = 0; c_ < 2; ++c_)                                        \
            _Pragma("unroll")                                                 \
            for (int k_ = 0; k_ < 2; ++k_)                                    \
                acc[MH][NH][r_][c_] = __builtin_amdgcn_mfma_f32_16x16x32_f16( \
                    ah[r_][k_], bh[c_][k_], acc[MH][NH][r_][c_], 0, 0, 0);    \
    __builtin_amdgcn_s_setprio(0);

// One K-tile (4 phases).  Buffer certified by previous tile's ENDW+barrier;
// ENDW certifies the next tile's buffer.
#define TILE_BLOCK(CUR, S1, S2, S3, S4, ENDW)                                 \
    {                                                                         \
        const f16* Bb = (CUR);                                                \
        /* p1: (m0,n0) */                                                     \
        RD_A(Bb, 0); RD_B(Bb, 0);                                             \
        S1;                                                                   \
        BARRIER; LG0; SCHED0;                                                 \
        MQ(0, 0);                                                             \
        SCHED0; LG0; BARRIER;                                                 \
        /* p2: (m0,n1) */                                                     \
        RD_B(Bb, 2048);                                                       \
        S2;                                                                   \
        BARRIER; LG0; SCHED0;                                                 \
        MQ(0, 1);                                                             \
        SCHED0; LG0; BARRIER;                                                 \
        /* p3: (m1,n1) */                                                     \
        RD_A(Bb, 4096);                                                       \
        S3;                                                                   \
        BARRIER; LG0; SCHED0;                                                 \
        MQ(1, 1);                                                             \
        SCHED0; LG0; BARRIER;                                                 \
        /* p4: (m1,n0) */                                                     \
        RD_B(Bb, 0);                                                          \
        S4;                                                                   \
        BARRIER; LG0; SCHED0;                                                 \
        MQ(1, 0);                                                             \
        SCHED0; LG0; ENDW; BARRIER;                                           \
    }

// MODE 0: P = X*X^T partials; finisher: X2 = -(sum), CT = 256*(X2/24 - X/6).
// MODE 1: P = X2*CT^T partials; finisher: OUT = I + X + X2/2 + sum/256.
template <int MODE>
__global__ __launch_bounds__(512, 2) void gemm8_kernel(
    const f16* __restrict__ Ap, const f16* __restrict__ BTp,
    f16* __restrict__ Pp, const f16* __restrict__ Xp,
    f16* __restrict__ X2p, f16* __restrict__ CTp,
    float* __restrict__ OUT, unsigned* __restrict__ cnt)
{
    extern __shared__ __align__(16) f16 lds[];
    constexpr int PLB  = 16384;   // B plane base (halfs) within a buffer
    constexpr int BUFH = 32768;   // halfs per K-tile buffer (64 KB)
    const size_t NN = (size_t)NM * NM;

    const int tid  = threadIdx.x;
    const int wave = tid >> 6, lane = tid & 63;
    const int wr = wave >> 2, wc = wave & 3;   // 2 x 4 waves, wave tile 128x64
    const int l15 = lane & 15, qq = lane >> 4;

    // XCD-aware decomposition: xcd -> (k-slice, row-half); 32 blocks per XCD
    // cover 4x8 tiles of one k-slice half (~3 MB L2 footprint per XCD).
    const int bid = blockIdx.x;
    const int xcd = bid & 7, li = bid >> 3;
    const int sk   = xcd >> 1;                   // split-K index 0..3
    const int trow = (xcd & 1) * 4 + (li >> 3);  // 0..7
    const int tcol = li & 7;                     // 0..7
    const int rowBase = trow * 256, colBase = tcol * 256;
    const int kBase = sk * 512;

    // Staging bases (load 0 of 2; load 1 = +128 rows, same swizzle).
    // Row m, physical chunk sp holds logical k-chunk sl = sp ^ (m&7).
    const f16* gsrc[4];
    int loff[4];
    {
        const int m = tid >> 3, sp = tid & 7;       // m in [0,64)
        const int rA0 = m;
        const int rA1 = 64 + m;
        const int rB0 = (m & 31) + ((m >> 5) << 6);
        const int rB1 = 32 + rB0;
        gsrc[0] = Ap  + (size_t)(rowBase + rA0) * NM + kBase + (sp ^ (rA0 & 7)) * 8;
        gsrc[1] = Ap  + (size_t)(rowBase + rA1) * NM + kBase + (sp ^ (rA1 & 7)) * 8;
        gsrc[2] = BTp + (size_t)(colBase + rB0) * NM + kBase + (sp ^ (rB0 & 7)) * 8;
        gsrc[3] = BTp + (size_t)(colBase + rB1) * NM + kBase + (sp ^ (rB1 & 7)) * 8;
        loff[0] = (rA0 * 8 + sp) * 8;
        loff[1] = (rA1 * 8 + sp) * 8;
        loff[2] = PLB + (rB0 * 8 + sp) * 8;
        loff[3] = PLB + (rB1 * 8 + sp) * 8;
    }

    // LDS fragment offsets (m-half 0 / n-half 0; +4096/+2048 halfs for half 1)
    int offA[4][2], offB[2][2];
    #pragma unroll
    for (int r = 0; r < 4; ++r)
        #pragma unroll
        for (int kk = 0; kk < 2; ++kk) {
            const int row = wr * 128 + r * 16 + l15;
            offA[r][kk] = (row * 8 + ((kk * 4 + qq) ^ (row & 7))) * 8;
        }
    #pragma unroll
    for (int c = 0; c < 2; ++c)
        #pragma unroll
        for (int kk = 0; kk < 2; ++kk) {
            const int row = wc * 64 + c * 16 + l15;
            offB[c][kk] = PLB + (row * 8 + ((kk * 4 + qq) ^ (row & 7))) * 8;
        }

    float4v acc[2][2][4][2];
    #pragma unroll
    for (int mh = 0; mh < 2; ++mh)
        #pragma unroll
        for (int nh = 0; nh < 2; ++nh)
            #pragma unroll
            for (int r = 0; r < 4; ++r)
                #pragma unroll
                for (int c = 0; c < 2; ++c)
                    acc[mh][nh][r][c] = (float4v){0.f, 0.f, 0.f, 0.f};

    half8 ah[4][2], bh[2][2];

    f16* B0 = lds;
    f16* B1 = lds + BUFH;

    // Prologue: tile0 all units, then u0(t1), u3(t1); own-wave vmcnt(4)
    // completes the 8 tile-0 loads, barrier certifies block-wide.
    STAGE_U(0, B0); STAGE_U(1, B0); STAGE_U(2, B0); STAGE_U(3, B0);
    STAGE_U(0, B1); STAGE_U(3, B1);
    W4; BARRIER;

    // Tiles 0..5 in pairs: tile T stages u1,u2 -> other buffer (T+1),
    // u0,u3 -> current buffer (T+2); end wait vmcnt(4) certifies T+1.
    #pragma unroll 1
    for (int i = 0; i < 3; ++i) {
        TILE_BLOCK(B0, STAGE_U(1, B1), STAGE_U(2, B1), STAGE_U(0, B0), STAGE_U(3, B0), W4)
        TILE_BLOCK(B1, STAGE_U(1, B0), STAGE_U(2, B0), STAGE_U(0, B1), STAGE_U(3, B1), W4)
    }
    // Peeled tail: tile 6 stages only u1,u2 of tile 7, ends with vmcnt(0).
    TILE_BLOCK(B0, STAGE_U(1, B1), STAGE_U(2, B1), NOST, NOST, W0)
    TILE_BLOCK(B1, NOST, NOST, NOST, NOST, NOST)

    // Partial-plane write (identical to round 3).  C/D: col=l15, row=qq*4+g.
    f16* dst = Pp + (size_t)sk * NN;
    #pragma unroll
    for (int mh = 0; mh < 2; ++mh)
        #pragma unroll
        for (int nh = 0; nh < 2; ++nh)
            #pragma unroll
            for (int r = 0; r < 4; ++r)
                #pragma unroll
                for (int c = 0; c < 2; ++c)
                    #pragma unroll
                    for (int g = 0; g < 4; ++g) {
                        const int row = rowBase + wr * 128 + mh * 64 + r * 16 + qq * 4 + g;
                        const int col = colBase + wc * 64 + nh * 32 + c * 16 + l15;
                        dst[(size_t)row * NM + col] = (f16)acc[mh][nh][r][c][g];
                    }

    // Ticket: last arriver of the 4 split-K siblings reduces this tile.
    __threadfence();
    __syncthreads();
    int* finp = (int*)lds;          // LDS reuse (GEMM phase fully done)
    if (tid == 0) {
        unsigned old = __hip_atomic_fetch_add(&cnt[trow * 8 + tcol], 1u,
                                              __ATOMIC_ACQ_REL,
                                              __HIP_MEMORY_SCOPE_AGENT);
        *finp = (old == 3u);
    }
    __syncthreads();
    if (!*finp) return;
    __threadfence();

    // Finisher: reduce the 4 partial planes over this 256x256 tile.
    // e = (row-rowBase)*32 + colchunk; consecutive tids -> coalesced 16B.
    for (int e = tid; e < 8192; e += 512) {
        const int row = rowBase + (e >> 5);
        const size_t i = (size_t)row * NM + colBase + (size_t)(e & 31) * 8;
        const half8 p0 = *(const half8*)(Pp + i);
        const half8 p1 = *(const half8*)(Pp + NN + i);
        const half8 p2 = *(const half8*)(Pp + 2 * NN + i);
        const half8 p3 = *(const half8*)(Pp + 3 * NN + i);
        const half8 xv = *(const half8*)(Xp + i);
        if (MODE == 0) {
            half8 x2v, ctv;
            #pragma unroll
            for (int j = 0; j < 8; ++j) {
                const float s  = (float)p0[j] + (float)p1[j] + (float)p2[j] + (float)p3[j];
                const float x2 = -s;
                const float x  = (float)xv[j];
                x2v[j] = (f16)x2;
                ctv[j] = (f16)(x2 * (256.0f / 24.0f) - x * (256.0f / 6.0f));
            }
            *(half8*)(X2p + i) = x2v;
            *(half8*)(CTp + i) = ctv;
        } else {
            const half8 x2v = *(const half8*)(X2p + i);
            float o[8];
            #pragma unroll
            for (int j = 0; j < 8; ++j) {
                const float q = (float)p0[j] + (float)p1[j] + (float)p2[j] + (float)p3[j];
                o[j] = (float)xv[j] + 0.5f * (float)x2v[j] + q * (1.0f / 256.0f);
            }
            const int j0 = colBase + (e & 31) * 8;
            if (row >= j0 && row < j0 + 8) o[row - j0] += 1.0f;
            *(float4v*)(OUT + i)     = (float4v){o[0], o[1], o[2], o[3]};
            *(float4v*)(OUT + i + 4) = (float4v){o[4], o[5], o[6], o[7]};
        }
    }
}

// ---------------------------------------------------------------------------
// exp(S) ~= T4(S) = I + X + X2/2 + X2*(X/6 + X2/24),  X = A - A^T.
// ws: X, X2, CT + 4 f16 partial planes (58.7 MB) + 128 u32 tile counters.
// ---------------------------------------------------------------------------
extern "C" void kernel_launch(void* const* d_in, const int* in_sizes, int n_in,
                              void* d_out, int out_size, void* d_ws, size_t ws_size,
                              hipStream_t stream) {
    const float* A = (const float*)d_in[0];
    float* out = (float*)d_out;
    const size_t NN = (size_t)NM * NM;

    f16* X  = (f16*)d_ws;
    f16* X2 = X + NN;
    f16* CT = X2 + NN;
    f16* P  = CT + NN;                     // 4 partial planes
    unsigned* cnt = (unsigned*)(P + 4 * NN);  // 128 u32 (64 per GEMM stage)

    static int attr_done = 0;
    if (!attr_done) {
        hipFuncSetAttribute((const void*)gemm8_kernel<0>,
                            hipFuncAttributeMaxDynamicSharedMemorySize, 131072);
        hipFuncSetAttribute((const void*)gemm8_kernel<1>,
                            hipFuncAttributeMaxDynamicSharedMemorySize, 131072);
        attr_done = 1;
    }

    // Tile counters must be zero each iteration (d_ws is re-poisoned).
    hipMemsetAsync(cnt, 0, 128 * sizeof(unsigned), stream);

    dim3 tb(32, 8), tg(NM / 32, NM / 32);
    // 1) X = A - A^T
    skew_f16_kernel<<<tg, tb, 0, stream>>>(A, X);
    // 2) partials of X*X^T (= -X2); finishers emit X2, CT
    gemm8_kernel<0><<<256, 512, 131072, stream>>>(X, X, P, X, X2, CT, nullptr, cnt);
    // 3) partials of X2*CT^T (= 256*X2*C); finishers emit OUT
    gemm8_kernel<1><<<256, 512, 131072, stream>>>(X2, CT, P, X, X2, CT, out, cnt + 64);
}

// Round 5
// 351.598 us; speedup vs baseline: 1.0016x; 1.0016x over previous
//
#include <hip/hip_runtime.h>
#include <stdint.h>

#define NM 2048

typedef _Float16 f16;
typedef __attribute__((ext_vector_type(8))) _Float16 half8;
typedef __attribute__((ext_vector_type(4))) float float4v;

// ---------------------------------------------------------------------------
// X = A - A^T  (f16).  |X| <~ 0.1 so f16 abs err < 4e-5/entry.
// ---------------------------------------------------------------------------
__global__ void skew_f16_kernel(const float* __restrict__ A, f16* __restrict__ X) {
    __shared__ float t[32][33];
    const int bx = blockIdx.x * 32, by = blockIdx.y * 32;
    const int tx = threadIdx.x, ty = threadIdx.y;
    #pragma unroll
    for (int r = 0; r < 32; r += 8)
        t[ty + r][tx] = A[(size_t)(bx + ty + r) * NM + by + tx];
    __syncthreads();
    #pragma unroll
    for (int r = 0; r < 32; r += 8) {
        const int i = by + ty + r, j = bx + tx;
        X[(size_t)i * NM + j] = (f16)(A[(size_t)i * NM + j] - t[tx][ty + r]);
    }
}

// ---------------------------------------------------------------------------
// 256x256-tile, BK=64, 8-wave 8-phase counted-vmcnt GEMM, split-K=4 ->
// 256 blocks (1/CU).  Round-5 changes vs round 4:
//  (1) __launch_bounds__(512, 1): round 1-4 used (512,2) which capped VGPRs
//      at 128 (4 waves/SIMD target) while the kernel needs ~165 -> ~40 VGPR
//      of scratch spills per thread in the MFMA loop (rocprof r4: VGPR=120,
//      all pipes idle, +25MB write / +8MB fetch of scratch traffic).  LDS
//      (128KB) allows only 1 block/CU anyway; cap at 256 VGPR, no spill.
//  (2) sched_barrier(0) pins REMOVED: m201 template needs none, and pins
//      extended ah/bh live ranges across pinned boundaries -> more spill.
// Schedule (correctness-verified rounds 3+4): per-tile vmcnt(4) at end of
// p4 between lgkmcnt(0) and closing barrier; tile reads only after {every
// wave's own vmcnt wait} -> barrier.  Last-arriver ticket fusion for the
// split-K reduce (no spinning -> deadlock-impossible).
// LDS: 2 x 64 KB buffers = 128 KB, 1 block/CU, 2 waves/SIMD.
// ---------------------------------------------------------------------------
#define BARRIER asm volatile("s_barrier" ::: "memory")
#define LG0     asm volatile("s_waitcnt lgkmcnt(0)" ::: "memory")
#define W4      asm volatile("s_waitcnt vmcnt(4)" ::: "memory")
#define W0      asm volatile("s_waitcnt vmcnt(0)" ::: "memory")
#define NOST    ((void)0)

#define STAGE_U(u, dst)                                                       \
    do {                                                                      \
        __builtin_amdgcn_global_load_lds(                                     \
            (const __attribute__((address_space(1))) void*)gsrc[u],           \
            (__attribute__((address_space(3))) void*)(uintptr_t)((dst) + loff[u]), \
            16, 0, 0);                                                        \
        __builtin_amdgcn_global_load_lds(                                     \
            (const __attribute__((address_space(1))) void*)(gsrc[u] + (size_t)128 * NM), \
            (__attribute__((address_space(3))) void*)(uintptr_t)((dst) + loff[u] + 8192), \
            16, 0, 0);                                                        \
        gsrc[u] += 64;                                                        \
    } while (0)

#define RD_A(BB, HOFF)                                                        \
    { _Pragma("unroll")                                                       \
      for (int r_ = 0; r_ < 4; ++r_)                                          \
        _Pragma("unroll")                                                     \
        for (int k_ = 0; k_ < 2; ++k_)                                        \
            ah[r_][k_] = *(const half8*)&(BB)[offA[r_][k_] + (HOFF)]; }

#define RD_B(BB, HOFF)                                                        \
    { _Pragma("unroll")                                                       \
      for (int c_ = 0; c_ < 2; ++c_)                                          \
        _Pragma("unroll")                                                     \
        for (int k_ = 0; k_ < 2; ++k_)                                        \
            bh[c_][k_] = *(const half8*)&(BB)[offB[c_][k_] + (HOFF)]; }

#define MQ(MH, NH)                                                            \
    __builtin_amdgcn_s_setprio(1);                                            \
    _Pragma("unroll")                                                         \
    for (int r_ = 0; r_ < 4; ++r_)                                            \
        _Pragma("unroll")                                                     \
        for (int c_ = 0; c_ < 2; ++c_)                                        \
            _Pragma("unroll")                                                 \
            for (int k_ = 0; k_ < 2; ++k_)                                    \
                acc[MH][NH][r_][c_] = __builtin_amdgcn_mfma_f32_16x16x32_f16( \
                    ah[r_][k_], bh[c_][k_], acc[MH][NH][r_][c_], 0, 0, 0);    \
    __builtin_amdgcn_s_setprio(0);

// One K-tile (4 phases).  Buffer certified by previous tile's ENDW+barrier;
// ENDW certifies the next tile's buffer.
#define TILE_BLOCK(CUR, S1, S2, S3, S4, ENDW)                                 \
    {                                                                         \
        const f16* Bb = (CUR);                                                \
        /* p1: (m0,n0) */                                                     \
        RD_A(Bb, 0); RD_B(Bb, 0);                                             \
        S1;                                                                   \
        BARRIER; LG0;                                                         \
        MQ(0, 0);                                                             \
        LG0; BARRIER;                                                         \
        /* p2: (m0,n1) */                                                     \
        RD_B(Bb, 2048);                                                       \
        S2;                                                                   \
        BARRIER; LG0;                                                         \
        MQ(0, 1);                                                             \
        LG0; BARRIER;                                                         \
        /* p3: (m1,n1) */                                                     \
        RD_A(Bb, 4096);                                                       \
        S3;                                                                   \
        BARRIER; LG0;                                                         \
        MQ(1, 1);                                                             \
        LG0; BARRIER;                                                         \
        /* p4: (m1,n0) */                                                     \
        RD_B(Bb, 0);                                                          \
        S4;                                                                   \
        BARRIER; LG0;                                                         \
        MQ(1, 0);                                                             \
        LG0; ENDW; BARRIER;                                                   \
    }

// MODE 0: P = X*X^T partials; finisher: X2 = -(sum), CT = 256*(X2/24 - X/6).
// MODE 1: P = X2*CT^T partials; finisher: OUT = I + X + X2/2 + sum/256.
template <int MODE>
__global__ __launch_bounds__(512, 1) void gemm8_kernel(
    const f16* __restrict__ Ap, const f16* __restrict__ BTp,
    f16* __restrict__ Pp, const f16* __restrict__ Xp,
    f16* __restrict__ X2p, f16* __restrict__ CTp,
    float* __restrict__ OUT, unsigned* __restrict__ cnt)
{
    extern __shared__ __align__(16) f16 lds[];
    constexpr int PLB  = 16384;   // B plane base (halfs) within a buffer
    constexpr int BUFH = 32768;   // halfs per K-tile buffer (64 KB)
    const size_t NN = (size_t)NM * NM;

    const int tid  = threadIdx.x;
    const int wave = tid >> 6, lane = tid & 63;
    const int wr = wave >> 2, wc = wave & 3;   // 2 x 4 waves, wave tile 128x64
    const int l15 = lane & 15, qq = lane >> 4;

    // XCD-aware decomposition: xcd -> (k-slice, row-half); 32 blocks per XCD
    // cover 4x8 tiles of one k-slice half (~3 MB L2 footprint per XCD).
    const int bid = blockIdx.x;
    const int xcd = bid & 7, li = bid >> 3;
    const int sk   = xcd >> 1;                   // split-K index 0..3
    const int trow = (xcd & 1) * 4 + (li >> 3);  // 0..7
    const int tcol = li & 7;                     // 0..7
    const int rowBase = trow * 256, colBase = tcol * 256;
    const int kBase = sk * 512;

    // Staging bases (load 0 of 2; load 1 = +128 rows, same swizzle).
    // Row m, physical chunk sp holds logical k-chunk sl = sp ^ (m&7).
    const f16* gsrc[4];
    int loff[4];
    {
        const int m = tid >> 3, sp = tid & 7;       // m in [0,64)
        const int rA0 = m;
        const int rA1 = 64 + m;
        const int rB0 = (m & 31) + ((m >> 5) << 6);
        const int rB1 = 32 + rB0;
        gsrc[0] = Ap  + (size_t)(rowBase + rA0) * NM + kBase + (sp ^ (rA0 & 7)) * 8;
        gsrc[1] = Ap  + (size_t)(rowBase + rA1) * NM + kBase + (sp ^ (rA1 & 7)) * 8;
        gsrc[2] = BTp + (size_t)(colBase + rB0) * NM + kBase + (sp ^ (rB0 & 7)) * 8;
        gsrc[3] = BTp + (size_t)(colBase + rB1) * NM + kBase + (sp ^ (rB1 & 7)) * 8;
        loff[0] = (rA0 * 8 + sp) * 8;
        loff[1] = (rA1 * 8 + sp) * 8;
        loff[2] = PLB + (rB0 * 8 + sp) * 8;
        loff[3] = PLB + (rB1 * 8 + sp) * 8;
    }

    // LDS fragment offsets (m-half 0 / n-half 0; +4096/+2048 halfs for half 1)
    int offA[4][2], offB[2][2];
    #pragma unroll
    for (int r = 0; r < 4; ++r)
        #pragma unroll
        for (int kk = 0; kk < 2; ++kk) {
            const int row = wr * 128 + r * 16 + l15;
            offA[r][kk] = (row * 8 + ((kk * 4 + qq) ^ (row & 7))) * 8;
        }
    #pragma unroll
    for (int c = 0; c < 2; ++c)
        #pragma unroll
        for (int kk = 0; kk < 2; ++kk) {
            const int row = wc * 64 + c * 16 + l15;
            offB[c][kk] = PLB + (row * 8 + ((kk * 4 + qq) ^ (row & 7))) * 8;
        }

    float4v acc[2][2][4][2];
    #pragma unroll
    for (int mh = 0; mh < 2; ++mh)
        #pragma unroll
        for (int nh = 0; nh < 2; ++nh)
            #pragma unroll
            for (int r = 0; r < 4; ++r)
                #pragma unroll
                for (int c = 0; c < 2; ++c)
                    acc[mh][nh][r][c] = (float4v){0.f, 0.f, 0.f, 0.f};

    half8 ah[4][2], bh[2][2];

    f16* B0 = lds;
    f16* B1 = lds + BUFH;

    // Prologue: tile0 all units, then u0(t1), u3(t1); own-wave vmcnt(4)
    // completes the 8 tile-0 loads, barrier certifies block-wide.
    STAGE_U(0, B0); STAGE_U(1, B0); STAGE_U(2, B0); STAGE_U(3, B0);
    STAGE_U(0, B1); STAGE_U(3, B1);
    W4; BARRIER;

    // Tiles 0..5 in pairs: tile T stages u1,u2 -> other buffer (T+1),
    // u0,u3 -> current buffer (T+2); end wait vmcnt(4) certifies T+1.
    #pragma unroll 1
    for (int i = 0; i < 3; ++i) {
        TILE_BLOCK(B0, STAGE_U(1, B1), STAGE_U(2, B1), STAGE_U(0, B0), STAGE_U(3, B0), W4)
        TILE_BLOCK(B1, STAGE_U(1, B0), STAGE_U(2, B0), STAGE_U(0, B1), STAGE_U(3, B1), W4)
    }
    // Peeled tail: tile 6 stages only u1,u2 of tile 7, ends with vmcnt(0).
    TILE_BLOCK(B0, STAGE_U(1, B1), STAGE_U(2, B1), NOST, NOST, W0)
    TILE_BLOCK(B1, NOST, NOST, NOST, NOST, NOST)

    // Partial-plane write.  C/D layout: col=l15, row=qq*4+g.
    f16* dst = Pp + (size_t)sk * NN;
    #pragma unroll
    for (int mh = 0; mh < 2; ++mh)
        #pragma unroll
        for (int nh = 0; nh < 2; ++nh)
            #pragma unroll
            for (int r = 0; r < 4; ++r)
                #pragma unroll
                for (int c = 0; c < 2; ++c)
                    #pragma unroll
                    for (int g = 0; g < 4; ++g) {
                        const int row = rowBase + wr * 128 + mh * 64 + r * 16 + qq * 4 + g;
                        const int col = colBase + wc * 64 + nh * 32 + c * 16 + l15;
                        dst[(size_t)row * NM + col] = (f16)acc[mh][nh][r][c][g];
                    }

    // Ticket: last arriver of the 4 split-K siblings reduces this tile.
    __threadfence();
    __syncthreads();
    int* finp = (int*)lds;          // LDS reuse (GEMM phase fully done)
    if (tid == 0) {
        unsigned old = __hip_atomic_fetch_add(&cnt[trow * 8 + tcol], 1u,
                                              __ATOMIC_ACQ_REL,
                                              __HIP_MEMORY_SCOPE_AGENT);
        *finp = (old == 3u);
    }
    __syncthreads();
    if (!*finp) return;
    __threadfence();

    // Finisher: reduce the 4 partial planes over this 256x256 tile.
    // e = (row-rowBase)*32 + colchunk; consecutive tids -> coalesced 16B.
    for (int e = tid; e < 8192; e += 512) {
        const int row = rowBase + (e >> 5);
        const size_t i = (size_t)row * NM + colBase + (size_t)(e & 31) * 8;
        const half8 p0 = *(const half8*)(Pp + i);
        const half8 p1 = *(const half8*)(Pp + NN + i);
        const half8 p2 = *(const half8*)(Pp + 2 * NN + i);
        const half8 p3 = *(const half8*)(Pp + 3 * NN + i);
        const half8 xv = *(const half8*)(Xp + i);
        if (MODE == 0) {
            half8 x2v, ctv;
            #pragma unroll
            for (int j = 0; j < 8; ++j) {
                const float s  = (float)p0[j] + (float)p1[j] + (float)p2[j] + (float)p3[j];
                const float x2 = -s;
                const float x  = (float)xv[j];
                x2v[j] = (f16)x2;
                ctv[j] = (f16)(x2 * (256.0f / 24.0f) - x * (256.0f / 6.0f));
            }
            *(half8*)(X2p + i) = x2v;
            *(half8*)(CTp + i) = ctv;
        } else {
            const half8 x2v = *(const half8*)(X2p + i);
            float o[8];
            #pragma unroll
            for (int j = 0; j < 8; ++j) {
                const float q = (float)p0[j] + (float)p1[j] + (float)p2[j] + (float)p3[j];
                o[j] = (float)xv[j] + 0.5f * (float)x2v[j] + q * (1.0f / 256.0f);
            }
            const int j0 = colBase + (e & 31) * 8;
            if (row >= j0 && row < j0 + 8) o[row - j0] += 1.0f;
            *(float4v*)(OUT + i)     = (float4v){o[0], o[1], o[2], o[3]};
            *(float4v*)(OUT + i + 4) = (float4v){o[4], o[5], o[6], o[7]};
        }
    }
}

// ---------------------------------------------------------------------------
// exp(S) ~= T4(S) = I + X + X2/2 + X2*(X/6 + X2/24),  X = A - A^T.
// ws: X, X2, CT + 4 f16 partial planes (58.7 MB) + 128 u32 tile counters.
// ---------------------------------------------------------------------------
extern "C" void kernel_launch(void* const* d_in, const int* in_sizes, int n_in,
                              void* d_out, int out_size, void* d_ws, size_t ws_size,
                              hipStream_t stream) {
    const float* A = (const float*)d_in[0];
    float* out = (float*)d_out;
    const size_t NN = (size_t)NM * NM;

    f16* X  = (f16*)d_ws;
    f16* X2 = X + NN;
    f16* CT = X2 + NN;
    f16* P  = CT + NN;                     // 4 partial planes
    unsigned* cnt = (unsigned*)(P + 4 * NN);  // 128 u32 (64 per GEMM stage)

    static int attr_done = 0;
    if (!attr_done) {
        hipFuncSetAttribute((const void*)gemm8_kernel<0>,
                            hipFuncAttributeMaxDynamicSharedMemorySize, 131072);
        hipFuncSetAttribute((const void*)gemm8_kernel<1>,
                            hipFuncAttributeMaxDynamicSharedMemorySize, 131072);
        attr_done = 1;
    }

    // Tile counters must be zero each iteration (d_ws is re-poisoned).
    hipMemsetAsync(cnt, 0, 128 * sizeof(unsigned), stream);

    dim3 tb(32, 8), tg(NM / 32, NM / 32);
    // 1) X = A - A^T
    skew_f16_kernel<<<tg, tb, 0, stream>>>(A, X);
    // 2) partials of X*X^T (= -X2); finishers emit X2, CT
    gemm8_kernel<0><<<256, 512, 131072, stream>>>(X, X, P, X, X2, CT, nullptr, cnt);
    // 3) partials of X2*CT^T (= 256*X2*C); finishers emit OUT
    gemm8_kernel<1><<<256, 512, 131072, stream>>>(X2, CT, P, X, X2, CT, out, cnt + 64);
}

// Round 6
// 137.146 us; speedup vs baseline: 2.5677x; 2.5637x over previous
//
#include <hip/hip_runtime.h>
#include <stdint.h>

#define NM 2048

typedef _Float16 f16;
typedef __attribute__((ext_vector_type(8))) _Float16 half8;
typedef __attribute__((ext_vector_type(4))) float float4v;

// ---------------------------------------------------------------------------
// X = A - A^T  (f16).  |X| <~ 0.1 so f16 abs err < 4e-5/entry.
// ---------------------------------------------------------------------------
__global__ void skew_f16_kernel(const float* __restrict__ A, f16* __restrict__ X) {
    __shared__ float t[32][33];
    const int bx = blockIdx.x * 32, by = blockIdx.y * 32;
    const int tx = threadIdx.x, ty = threadIdx.y;
    #pragma unroll
    for (int r = 0; r < 32; r += 8)
        t[ty + r][tx] = A[(size_t)(bx + ty + r) * NM + by + tx];
    __syncthreads();
    #pragma unroll
    for (int r = 0; r < 32; r += 8) {
        const int i = by + ty + r, j = bx + tx;
        X[(size_t)i * NM + j] = (f16)(A[(size_t)i * NM + j] - t[tx][ty + r]);
    }
}

// ---------------------------------------------------------------------------
// 256x256-tile, BK=64, 8-wave GEMM, split-K=4 -> 256 blocks (1/CU).
// Round-6: (a) ticket fusion REVERTED (r4/r5 A/B: all-thread __threadfence
// = per-wave L2 writebacks, +120us/GEMM; separate reduce kernels are ~10us
// each); (b) 2 phases per K-tile (was 4): ph1 = A-m0 x B-all (16 ds_read,
// 32 MFMA; B fragments stay live in regs), ph2 = A-m1 x same B (8 ds_read,
// 32 MFMA).  Halves the per-phase fixed tax (barriers/sync) per MFMA.
//
// Staging units: u0=A-m0 rows{0..63,128..191}, u1=A-m1 {64..127,192..255},
// u2=B{0..31,64..95,...}, u3=B{32..63,96..127,...}.  Last read: u0,u2,u3
// in ph1; u1 in ph2.  Stage slots tile T: u1(T+1)@T.ph1 (other buffer,
// WAR-certified by T-1's end barrier), u0,u2,u3(T+2)@T.ph2 (current
// buffer, after ph1's closing barrier = their last reads certified).
// End-of-tile wait at T.ph2 after issuing its 6 stages: outstanding =
// {u0,u2,u3(T+1) from T-1.ph2} + {u1(T+1) from T.ph1} + {6 new} ->
// vmcnt(6) retires exactly tile T+1's 8 loads.  Never drains to 0 until
// the tail.  vmcnt is per-wave: every buffer read sits after {each wave's
// own wait} -> barrier (round-2 lesson).
// LDS: 2 x 64 KB buffers = 128 KB, 1 block/CU, 2 waves/SIMD.
// ---------------------------------------------------------------------------
#define BARRIER asm volatile("s_barrier" ::: "memory")
#define LG0     asm volatile("s_waitcnt lgkmcnt(0)" ::: "memory")
#define W6      asm volatile("s_waitcnt vmcnt(6)" ::: "memory")
#define W0      asm volatile("s_waitcnt vmcnt(0)" ::: "memory")
#define NOST    ((void)0)

#define STAGE_U(u, dst)                                                       \
    do {                                                                      \
        __builtin_amdgcn_global_load_lds(                                     \
            (const __attribute__((address_space(1))) void*)gsrc[u],           \
            (__attribute__((address_space(3))) void*)(uintptr_t)((dst) + loff[u]), \
            16, 0, 0);                                                        \
        __builtin_amdgcn_global_load_lds(                                     \
            (const __attribute__((address_space(1))) void*)(gsrc[u] + (size_t)128 * NM), \
            (__attribute__((address_space(3))) void*)(uintptr_t)((dst) + loff[u] + 8192), \
            16, 0, 0);                                                        \
        gsrc[u] += 64;                                                        \
    } while (0)

// ah: one m-half (8 reads); bh: both n-halves (8 reads).
#define RD_AH(BB, HOFF)                                                       \
    { _Pragma("unroll")                                                       \
      for (int r_ = 0; r_ < 4; ++r_)                                          \
        _Pragma("unroll")                                                     \
        for (int k_ = 0; k_ < 2; ++k_)                                        \
            ah[r_][k_] = *(const half8*)&(BB)[offA[r_][k_] + (HOFF)]; }

#define RD_BH(BB)                                                             \
    { _Pragma("unroll")                                                       \
      for (int n_ = 0; n_ < 2; ++n_)                                          \
        _Pragma("unroll")                                                     \
        for (int c_ = 0; c_ < 2; ++c_)                                        \
            _Pragma("unroll")                                                 \
            for (int k_ = 0; k_ < 2; ++k_)                                    \
                bh[n_][c_][k_] = *(const half8*)&(BB)[offB[c_][k_] + n_ * 2048]; }

// One m-half phase: 32 MFMA (all n) into acc[MH][*][*][*].
#define MPH(MH)                                                               \
    __builtin_amdgcn_s_setprio(1);                                            \
    _Pragma("unroll")                                                         \
    for (int n_ = 0; n_ < 2; ++n_)                                            \
        _Pragma("unroll")                                                     \
        for (int r_ = 0; r_ < 4; ++r_)                                        \
            _Pragma("unroll")                                                 \
            for (int c_ = 0; c_ < 2; ++c_)                                    \
                _Pragma("unroll")                                             \
                for (int k_ = 0; k_ < 2; ++k_)                                \
                    acc[MH][n_][r_][c_] = __builtin_amdgcn_mfma_f32_16x16x32_f16( \
                        ah[r_][k_], bh[n_][c_][k_], acc[MH][n_][r_][c_], 0, 0, 0); \
    __builtin_amdgcn_s_setprio(0);

// One K-tile (2 phases).  S1 = stage u1(T+1)->other; S2 = stage
// u0,u2,u3(T+2)->current; WEND certifies the next tile's buffer.
#define TILE2(CUR, S1, S2, WEND)                                              \
    {                                                                         \
        const f16* Bb = (CUR);                                                \
        /* ph1: mh=0; reads A-m0 + B-all */                                   \
        RD_AH(Bb, 0); RD_BH(Bb);                                              \
        S1;                                                                   \
        BARRIER; LG0;                                                         \
        MPH(0);                                                               \
        BARRIER;                                                              \
        /* ph2: mh=1; reads A-m1 (bh still live) */                           \
        RD_AH(Bb, 4096);                                                      \
        S2;                                                                   \
        BARRIER; LG0;                                                         \
        MPH(1);                                                               \
        WEND; BARRIER;                                                        \
    }

__global__ __launch_bounds__(512, 1) void gemm8_kernel(
    const f16* __restrict__ Ap, const f16* __restrict__ BTp, f16* __restrict__ Pp)
{
    extern __shared__ __align__(16) f16 lds[];
    constexpr int PLB  = 16384;   // B plane base (halfs) within a buffer
    constexpr int BUFH = 32768;   // halfs per K-tile buffer (64 KB)

    const int tid  = threadIdx.x;
    const int wave = tid >> 6, lane = tid & 63;
    const int wr = wave >> 2, wc = wave & 3;   // 2 x 4 waves, wave tile 128x64
    const int l15 = lane & 15, qq = lane >> 4;

    // XCD-aware decomposition: xcd -> (k-slice, row-half); 32 blocks per XCD
    // cover 4x8 tiles of one k-slice half (~3 MB L2 footprint per XCD).
    const int bid = blockIdx.x;
    const int xcd = bid & 7, li = bid >> 3;
    const int sk   = xcd >> 1;                   // split-K index 0..3
    const int trow = (xcd & 1) * 4 + (li >> 3);  // 0..7
    const int tcol = li & 7;                     // 0..7
    const int rowBase = trow * 256, colBase = tcol * 256;
    const int kBase = sk * 512;

    // Staging bases (load 0 of 2; load 1 = +128 rows, same swizzle).
    // Row m, physical chunk sp holds logical k-chunk sl = sp ^ (m&7).
    const f16* gsrc[4];
    int loff[4];
    {
        const int m = tid >> 3, sp = tid & 7;       // m in [0,64)
        const int rA0 = m;
        const int rA1 = 64 + m;
        const int rB0 = (m & 31) + ((m >> 5) << 6);
        const int rB1 = 32 + rB0;
        gsrc[0] = Ap  + (size_t)(rowBase + rA0) * NM + kBase + (sp ^ (rA0 & 7)) * 8;
        gsrc[1] = Ap  + (size_t)(rowBase + rA1) * NM + kBase + (sp ^ (rA1 & 7)) * 8;
        gsrc[2] = BTp + (size_t)(colBase + rB0) * NM + kBase + (sp ^ (rB0 & 7)) * 8;
        gsrc[3] = BTp + (size_t)(colBase + rB1) * NM + kBase + (sp ^ (rB1 & 7)) * 8;
        loff[0] = (rA0 * 8 + sp) * 8;
        loff[1] = (rA1 * 8 + sp) * 8;
        loff[2] = PLB + (rB0 * 8 + sp) * 8;
        loff[3] = PLB + (rB1 * 8 + sp) * 8;
    }

    // LDS fragment offsets (m-half 0 / n-half 0; +4096/+2048 halfs for half 1;
    // swizzle invariant under +64/+32 rows since (row&7) unchanged).
    int offA[4][2], offB[2][2];
    #pragma unroll
    for (int r = 0; r < 4; ++r)
        #pragma unroll
        for (int kk = 0; kk < 2; ++kk) {
            const int row = wr * 128 + r * 16 + l15;
            offA[r][kk] = (row * 8 + ((kk * 4 + qq) ^ (row & 7))) * 8;
        }
    #pragma unroll
    for (int c = 0; c < 2; ++c)
        #pragma unroll
        for (int kk = 0; kk < 2; ++kk) {
            const int row = wc * 64 + c * 16 + l15;
            offB[c][kk] = PLB + (row * 8 + ((kk * 4 + qq) ^ (row & 7))) * 8;
        }

    float4v acc[2][2][4][2];
    #pragma unroll
    for (int mh = 0; mh < 2; ++mh)
        #pragma unroll
        for (int nh = 0; nh < 2; ++nh)
            #pragma unroll
            for (int r = 0; r < 4; ++r)
                #pragma unroll
                for (int c = 0; c < 2; ++c)
                    acc[mh][nh][r][c] = (float4v){0.f, 0.f, 0.f, 0.f};

    half8 ah[4][2], bh[2][2][2];

    f16* B0 = lds;
    f16* B1 = lds + BUFH;

    // Prologue: tile0 all units (8 loads) + u0,u2,u3 of tile1 (6 loads);
    // own-wave vmcnt(6) retires tile-0's 8 oldest; barrier certifies.
    STAGE_U(0, B0); STAGE_U(1, B0); STAGE_U(2, B0); STAGE_U(3, B0);
    STAGE_U(0, B1); STAGE_U(2, B1); STAGE_U(3, B1);
    W6; BARRIER;

    // Tiles 0..5 in pairs.
    #pragma unroll 1
    for (int i = 0; i < 3; ++i) {
        TILE2(B0, STAGE_U(1, B1),
              { STAGE_U(0, B0); STAGE_U(2, B0); STAGE_U(3, B0); }, W6)
        TILE2(B1, STAGE_U(1, B0),
              { STAGE_U(0, B1); STAGE_U(2, B1); STAGE_U(3, B1); }, W6)
    }
    // Tail: tile 6 stages only u1(t7), drains (no newer loads after);
    // tile 7 stages nothing, no wait.
    TILE2(B0, STAGE_U(1, B1), NOST, W0)
    TILE2(B1, NOST, NOST, NOST)

    // Epilogue: f16 partial plane.  C/D layout: col=lane&15, row=qq*4+g.
    f16* dst = Pp + (size_t)sk * NM * NM;
    #pragma unroll
    for (int mh = 0; mh < 2; ++mh)
        #pragma unroll
        for (int nh = 0; nh < 2; ++nh)
            #pragma unroll
            for (int r = 0; r < 4; ++r)
                #pragma unroll
                for (int c = 0; c < 2; ++c)
                    #pragma unroll
                    for (int g = 0; g < 4; ++g) {
                        const int row = rowBase + wr * 128 + mh * 64 + r * 16 + qq * 4 + g;
                        const int col = colBase + wc * 64 + nh * 32 + c * 16 + l15;
                        dst[(size_t)row * NM + col] = (f16)acc[mh][nh][r][c][g];
                    }
}

// ---------------------------------------------------------------------------
// reduce0: X2 = -(sum of 4 partials of X*X^T);  CT = 256*C^T where
//          C = X/6 + X2/24  ->  CT[i,j] = 256*(X2[i,j]/24 - X[i,j]/6).
// ---------------------------------------------------------------------------
__global__ __launch_bounds__(256) void reduce0_kernel(
    const f16* __restrict__ P, const f16* __restrict__ X,
    f16* __restrict__ X2, f16* __restrict__ CT)
{
    const size_t NN = (size_t)NM * NM;
    const size_t i = ((size_t)blockIdx.x * 256 + threadIdx.x) * 8;
    const half8 p0 = *(const half8*)(P + i);
    const half8 p1 = *(const half8*)(P + NN + i);
    const half8 p2 = *(const half8*)(P + 2 * NN + i);
    const half8 p3 = *(const half8*)(P + 3 * NN + i);
    const half8 xv = *(const half8*)(X + i);
    half8 x2v, ctv;
    #pragma unroll
    for (int j = 0; j < 8; ++j) {
        const float s  = (float)p0[j] + (float)p1[j] + (float)p2[j] + (float)p3[j];
        const float x2 = -s;
        const float x  = (float)xv[j];
        x2v[j] = (f16)x2;
        ctv[j] = (f16)(x2 * (256.0f / 24.0f) - x * (256.0f / 6.0f));
    }
    *(half8*)(X2 + i) = x2v;
    *(half8*)(CT + i) = ctv;
}

// ---------------------------------------------------------------------------
// reduce1: OUT = I + X + X2/2 + (sum of 4 partials of 256*X2*C)/256   (fp32)
// ---------------------------------------------------------------------------
__global__ __launch_bounds__(256) void reduce1_kernel(
    const f16* __restrict__ P, const f16* __restrict__ X,
    const f16* __restrict__ X2, float* __restrict__ OUT)
{
    const size_t NN = (size_t)NM * NM;
    const size_t i = ((size_t)blockIdx.x * 256 + threadIdx.x) * 8;
    const half8 p0  = *(const half8*)(P + i);
    const half8 p1  = *(const half8*)(P + NN + i);
    const half8 p2  = *(const half8*)(P + 2 * NN + i);
    const half8 p3  = *(const half8*)(P + 3 * NN + i);
    const half8 xv  = *(const half8*)(X + i);
    const half8 x2v = *(const half8*)(X2 + i);
    float o[8];
    #pragma unroll
    for (int j = 0; j < 8; ++j) {
        const float q = (float)p0[j] + (float)p1[j] + (float)p2[j] + (float)p3[j];
        o[j] = (float)xv[j] + 0.5f * (float)x2v[j] + q * (1.0f / 256.0f);
    }
    const int row = (int)(i >> 11), col0 = (int)(i & 2047);
    if (row >= col0 && row < col0 + 8) o[row - col0] += 1.0f;
    *(float4v*)(OUT + i)     = (float4v){o[0], o[1], o[2], o[3]};
    *(float4v*)(OUT + i + 4) = (float4v){o[4], o[5], o[6], o[7]};
}

// ---------------------------------------------------------------------------
// exp(S) ~= T4(S) = I + X + X2/2 + X2*(X/6 + X2/24),  X = A - A^T.
// ws: X, X2, CT + 4 f16 partial planes = 7 * 8.4 MB = 58.7 MB.
// ---------------------------------------------------------------------------
extern "C" void kernel_launch(void* const* d_in, const int* in_sizes, int n_in,
                              void* d_out, int out_size, void* d_ws, size_t ws_size,
                              hipStream_t stream) {
    const float* A = (const float*)d_in[0];
    float* out = (float*)d_out;
    const size_t NN = (size_t)NM * NM;

    f16* X  = (f16*)d_ws;
    f16* X2 = X + NN;
    f16* CT = X2 + NN;
    f16* P  = CT + NN;   // 4 partial planes

    static int attr_done = 0;
    if (!attr_done) {
        hipFuncSetAttribute((const void*)gemm8_kernel,
                            hipFuncAttributeMaxDynamicSharedMemorySize, 131072);
        attr_done = 1;
    }

    dim3 tb(32, 8), tg(NM / 32, NM / 32);
    // 1) X = A - A^T
    skew_f16_kernel<<<tg, tb, 0, stream>>>(A, X);
    // 2) partials of X*X^T (= -X2)
    gemm8_kernel<<<256, 512, 131072, stream>>>(X, X, P);
    // 3) X2, CT
    reduce0_kernel<<<2048, 256, 0, stream>>>(P, X, X2, CT);
    // 4) partials of X2*CT^T (= 256*X2*C)
    gemm8_kernel<<<256, 512, 131072, stream>>>(X2, CT, P);
    // 5) OUT = I + X + X2/2 + v/256
    reduce1_kernel<<<2048, 256, 0, stream>>>(P, X, X2, out);
}

// Round 7
// 122.676 us; speedup vs baseline: 2.8706x; 1.1180x over previous
//
#include <hip/hip_runtime.h>
#include <stdint.h>

#define NM 2048

typedef _Float16 f16;
typedef __attribute__((ext_vector_type(8))) _Float16 half8;
typedef __attribute__((ext_vector_type(4))) float float4v;

// ---------------------------------------------------------------------------
// X = A - A^T  (f16).  |X| <~ 0.1 so f16 abs err < 4e-5/entry.
// ---------------------------------------------------------------------------
__global__ void skew_f16_kernel(const float* __restrict__ A, f16* __restrict__ X) {
    __shared__ float t[32][33];
    const int bx = blockIdx.x * 32, by = blockIdx.y * 32;
    const int tx = threadIdx.x, ty = threadIdx.y;
    #pragma unroll
    for (int r = 0; r < 32; r += 8)
        t[ty + r][tx] = A[(size_t)(bx + ty + r) * NM + by + tx];
    __syncthreads();
    #pragma unroll
    for (int r = 0; r < 32; r += 8) {
        const int i = by + ty + r, j = bx + tx;
        X[(size_t)i * NM + j] = (f16)(A[(size_t)i * NM + j] - t[tx][ty + r]);
    }
}

// ---------------------------------------------------------------------------
// Round-7: NO cross-block split-K (r6 lesson: split-K's reduce kernels +
// 64MB partial-plane traffic cost ~20us and the schedule wins were nil).
// 128x128 tile, grid 16x16 = 256 blocks = 1/CU full chip, K=2048 = 32
// K-tiles/block, fused epilogue (block owns its output tile, r0-style).
// K-loop keeps the r6 discipline: BK=64, 2 phases/tile (ph1 = A-mhalf0 x
// B-all with B frags held in regs; ph2 = A-mhalf1), 2-tile-deep prefetch,
// counted vmcnt, XOR-swizzled LDS, XCD-aware block mapping.
//
// Units: uA0 = A rows{0..31,64..95} (read ph1), uA1 = A{32..63,96..127}
// (read ph2), uB = B all (read ph1 only; 2 loads/thread).  Stage slots for
// tile T: uA1(T+1)@T.ph1 -> other buf (prev occupant last read T-1.ph2,
// certified by its closing barrier); {uA0,uB}(T+2)@T.ph2 -> current buf
// (last read T.ph1, certified by ph1's closing barrier).  End-of-tile wait:
// outstanding = 3 (T+1 from T-1.ph2) + 1 (uA1(T+1) from T.ph1) + 3 (T+2
// from T.ph2) = 7 -> vmcnt(3) retires exactly T+1's 4 loads.  vmcnt is
// per-wave: every buffer read sits after {each wave's own wait} -> barrier.
// LDS: 2 x 32 KB buffers = 64 KB.
// ---------------------------------------------------------------------------
#define BARRIER asm volatile("s_barrier" ::: "memory")
#define LG0     asm volatile("s_waitcnt lgkmcnt(0)" ::: "memory")
#define W3      asm volatile("s_waitcnt vmcnt(3)" ::: "memory")
#define W0      asm volatile("s_waitcnt vmcnt(0)" ::: "memory")
#define NOST    ((void)0)

#define STAGE_1(u, dst)                                                       \
    do {                                                                      \
        __builtin_amdgcn_global_load_lds(                                     \
            (const __attribute__((address_space(1))) void*)gsrc[u],           \
            (__attribute__((address_space(3))) void*)(uintptr_t)((dst) + loff[u]), \
            16, 0, 0);                                                        \
        gsrc[u] += 64;                                                        \
    } while (0)

#define RD_A(BB, HOFF)                                                       \
    { _Pragma("unroll")                                                      \
      for (int r_ = 0; r_ < 2; ++r_)                                         \
        _Pragma("unroll")                                                    \
        for (int k_ = 0; k_ < 2; ++k_)                                       \
            ah[r_][k_] = *(const half8*)&(BB)[offA[r_][k_] + (HOFF)]; }

#define RD_B(BB)                                                             \
    { _Pragma("unroll")                                                      \
      for (int c_ = 0; c_ < 2; ++c_)                                         \
        _Pragma("unroll")                                                    \
        for (int k_ = 0; k_ < 2; ++k_)                                       \
            bh[c_][k_] = *(const half8*)&(BB)[offB[c_][k_]]; }

#define MPH(MH)                                                              \
    __builtin_amdgcn_s_setprio(1);                                           \
    _Pragma("unroll")                                                        \
    for (int r_ = 0; r_ < 2; ++r_)                                           \
        _Pragma("unroll")                                                    \
        for (int c_ = 0; c_ < 2; ++c_)                                       \
            _Pragma("unroll")                                                 \
            for (int k_ = 0; k_ < 2; ++k_)                                   \
                acc[MH][r_][c_] = __builtin_amdgcn_mfma_f32_16x16x32_f16(    \
                    ah[r_][k_], bh[c_][k_], acc[MH][r_][c_], 0, 0, 0);       \
    __builtin_amdgcn_s_setprio(0);

// One K-tile (2 phases).  S1 = stage uA1(T+1)->other; S2 = stage
// uA0,uB(T+2)->current; WEND certifies the next tile's buffer.
#define TILE2(CUR, S1, S2, WEND)                                             \
    {                                                                        \
        const f16* Bb = (CUR);                                               \
        /* ph1: A-mhalf0 x B-all */                                          \
        RD_A(Bb, 0); RD_B(Bb);                                               \
        S1;                                                                  \
        BARRIER; LG0;                                                        \
        MPH(0);                                                              \
        BARRIER;                                                             \
        /* ph2: A-mhalf1 (bh still live in regs) */                          \
        RD_A(Bb, 2048);                                                      \
        S2;                                                                  \
        BARRIER; LG0;                                                        \
        MPH(1);                                                              \
        WEND; BARRIER;                                                       \
    }

// MODE 0: A=BT=X; P = X*X^T = -X2.  Epilogue: X2 = -P (f16),
//         CT = 256*C^T = 256*(X2/24 - X/6) (f16).
// MODE 1: A=X2, BT=CT; P = 256*X2*C.  Epilogue: OUT = I + X + X2/2 + P/256.
template <int MODE>
__global__ __launch_bounds__(512, 1) void gemm_fused_kernel(
    const f16* __restrict__ Ap, const f16* __restrict__ BTp,
    const f16* __restrict__ Xp, f16* __restrict__ X2p,
    f16* __restrict__ CTp, float* __restrict__ OUT)
{
    extern __shared__ __align__(16) f16 lds[];
    constexpr int PLB  = 8192;    // B plane base (halfs) within a buffer
    constexpr int BUFH = 16384;   // halfs per K-tile buffer (32 KB)

    const int tid  = threadIdx.x;
    const int wave = tid >> 6, lane = tid & 63;
    const int wr = wave >> 2, wc = wave & 3;   // 2 x 4 waves, wave tile 64x32
    const int l15 = lane & 15, qq = lane >> 4;

    // XCD-aware mapping: 16x16 tiles; each XCD gets a 4x8 rectangle.
    const int bid = blockIdx.x;
    const int xcd = bid & 7, li = bid >> 3;            // 32 blocks/XCD
    const int trow = (xcd & 3) * 4 + (li >> 3);        // 0..15
    const int tcol = (xcd >> 2) * 8 + (li & 7);        // 0..15
    const int rowBase = trow * 128, colBase = tcol * 128;

    // Staging: row m, physical chunk sp holds logical k-chunk sp ^ (m&7).
    // u0=uA0 rows{0..31,64..95}, u1=uA1 rows{32..63,96..127},
    // u2=uB rows 0..63, u3=uB rows 64..127.  1 load (16B) per thread each.
    const f16* gsrc[4];
    int loff[4];
    {
        const int m = tid >> 3, sp = tid & 7;          // m in [0,64)
        const int rA0 = (m & 31) + ((m >> 5) << 6);    // {0..31, 64..95}
        const int rA1 = 32 + rA0;                      // {32..63, 96..127}
        const int rB0 = m;                             // 0..63
        const int rB1 = 64 + m;                        // 64..127
        gsrc[0] = Ap  + (size_t)(rowBase + rA0) * NM + (sp ^ (rA0 & 7)) * 8;
        gsrc[1] = Ap  + (size_t)(rowBase + rA1) * NM + (sp ^ (rA1 & 7)) * 8;
        gsrc[2] = BTp + (size_t)(colBase + rB0) * NM + (sp ^ (rB0 & 7)) * 8;
        gsrc[3] = BTp + (size_t)(colBase + rB1) * NM + (sp ^ (rB1 & 7)) * 8;
        loff[0] = (rA0 * 8 + sp) * 8;
        loff[1] = (rA1 * 8 + sp) * 8;
        loff[2] = PLB + (rB0 * 8 + sp) * 8;
        loff[3] = PLB + (rB1 * 8 + sp) * 8;
    }

    // Fragment LDS offsets.  A row (mh=0): wr*64 + r*16 + l15; mh=1 adds 32
    // rows = +2048 halfs (swizzle invariant: (row&7) unchanged by +32).
    int offA[2][2], offB[2][2];
    #pragma unroll
    for (int r = 0; r < 2; ++r)
        #pragma unroll
        for (int kk = 0; kk < 2; ++kk) {
            const int row = wr * 64 + r * 16 + l15;
            offA[r][kk] = (row * 8 + ((kk * 4 + qq) ^ (row & 7))) * 8;
        }
    #pragma unroll
    for (int c = 0; c < 2; ++c)
        #pragma unroll
        for (int kk = 0; kk < 2; ++kk) {
            const int row = wc * 32 + c * 16 + l15;
            offB[c][kk] = PLB + (row * 8 + ((kk * 4 + qq) ^ (row & 7))) * 8;
        }

    float4v acc[2][2][2];
    #pragma unroll
    for (int mh = 0; mh < 2; ++mh)
        #pragma unroll
        for (int r = 0; r < 2; ++r)
            #pragma unroll
            for (int c = 0; c < 2; ++c)
                acc[mh][r][c] = (float4v){0.f, 0.f, 0.f, 0.f};

    half8 ah[2][2], bh[2][2];

    f16* B0 = lds;
    f16* B1 = lds + BUFH;

    // Prologue: tile0 all 4 loads, then uA0,uB(t1) (3 loads, oldest-first);
    // own-wave vmcnt(3) retires tile-0's 4; barrier certifies block-wide.
    STAGE_1(0, B0); STAGE_1(1, B0); STAGE_1(2, B0); STAGE_1(3, B0);
    STAGE_1(0, B1); STAGE_1(2, B1); STAGE_1(3, B1);
    W3; BARRIER;

    // Tiles 0..29 in pairs (15 iterations).
    #pragma unroll 1
    for (int i = 0; i < 15; ++i) {
        TILE2(B0, STAGE_1(1, B1),
              { STAGE_1(0, B0); STAGE_1(2, B0); STAGE_1(3, B0); }, W3)
        TILE2(B1, STAGE_1(1, B0),
              { STAGE_1(0, B1); STAGE_1(2, B1); STAGE_1(3, B1); }, W3)
    }
    // Tail: tile 30 stages only uA1(31) and drains; tile 31 stages nothing.
    TILE2(B0, STAGE_1(1, B1), NOST, W0)
    TILE2(B1, NOST, NOST, NOST)

    // Fused epilogue.  C/D layout: col = lane&15, row = qq*4 + g.
    #pragma unroll
    for (int mh = 0; mh < 2; ++mh)
        #pragma unroll
        for (int r = 0; r < 2; ++r)
            #pragma unroll
            for (int c = 0; c < 2; ++c)
                #pragma unroll
                for (int g = 0; g < 4; ++g) {
                    const int row = rowBase + wr * 64 + mh * 32 + r * 16 + qq * 4 + g;
                    const int col = colBase + wc * 32 + c * 16 + l15;
                    const size_t off = (size_t)row * NM + col;
                    const float p = acc[mh][r][c][g];
                    if (MODE == 0) {
                        const float v = -p;               // X2 = -(X*X^T)
                        const float x = (float)Xp[off];
                        X2p[off] = (f16)v;
                        CTp[off] = (f16)(v * (256.0f / 24.0f) - x * (256.0f / 6.0f));
                    } else {
                        const float x  = (float)Xp[off];
                        const float x2 = (float)X2p[off];
                        float o = x + 0.5f * x2 + p * (1.0f / 256.0f);
                        if (row == col) o += 1.0f;
                        OUT[off] = o;
                    }
                }
}

// ---------------------------------------------------------------------------
// exp(S) ~= T4(S) = I + X + X2/2 + X2*(X/6 + X2/24),  X = A - A^T.
// ws: X, X2, CT f16 planes = 25.2 MB.  3 dispatches, no reduce kernels.
// ---------------------------------------------------------------------------
extern "C" void kernel_launch(void* const* d_in, const int* in_sizes, int n_in,
                              void* d_out, int out_size, void* d_ws, size_t ws_size,
                              hipStream_t stream) {
    const float* A = (const float*)d_in[0];
    float* out = (float*)d_out;
    const size_t NN = (size_t)NM * NM;

    f16* X  = (f16*)d_ws;
    f16* X2 = X + NN;
    f16* CT = X2 + NN;

    static int attr_done = 0;
    if (!attr_done) {
        hipFuncSetAttribute((const void*)gemm_fused_kernel<0>,
                            hipFuncAttributeMaxDynamicSharedMemorySize, 65536);
        hipFuncSetAttribute((const void*)gemm_fused_kernel<1>,
                            hipFuncAttributeMaxDynamicSharedMemorySize, 65536);
        attr_done = 1;
    }

    dim3 tb(32, 8), tg(NM / 32, NM / 32);
    // 1) X = A - A^T
    skew_f16_kernel<<<tg, tb, 0, stream>>>(A, X);
    // 2) X2 = X*X (via -X*X^T), fused CT = 256*(X2/24 - X/6)
    gemm_fused_kernel<0><<<256, 512, 65536, stream>>>(X, X, X, X2, CT, nullptr);
    // 3) OUT = I + X + X2/2 + (X2*CT^T)/256
    gemm_fused_kernel<1><<<256, 512, 65536, stream>>>(X2, CT, X, X2, nullptr, out);
}

// Round 8
// 118.795 us; speedup vs baseline: 2.9643x; 1.0327x over previous
//
#include <hip/hip_runtime.h>
#include <stdint.h>

#define NM 2048

typedef _Float16 f16;
typedef __attribute__((ext_vector_type(8))) _Float16 half8;
typedef __attribute__((ext_vector_type(4))) float float4v;

// ---------------------------------------------------------------------------
// X = A - A^T  (f16).  |X| <~ 0.1 so f16 abs err < 4e-5/entry.
// ---------------------------------------------------------------------------
__global__ void skew_f16_kernel(const float* __restrict__ A, f16* __restrict__ X) {
    __shared__ float t[32][33];
    const int bx = blockIdx.x * 32, by = blockIdx.y * 32;
    const int tx = threadIdx.x, ty = threadIdx.y;
    #pragma unroll
    for (int r = 0; r < 32; r += 8)
        t[ty + r][tx] = A[(size_t)(bx + ty + r) * NM + by + tx];
    __syncthreads();
    #pragma unroll
    for (int r = 0; r < 32; r += 8) {
        const int i = by + ty + r, j = bx + tx;
        X[(size_t)i * NM + j] = (f16)(A[(size_t)i * NM + j] - t[tx][ty + r]);
    }
}

// ---------------------------------------------------------------------------
// Round-8: CO-RESIDENCY.  r0..r7 all plateau at ~50us/GEMM; the ladder's own
// shape curve (320 TF @2048 vs 833 @4096 for the same kernel) tracks
// blocks/CU (1 vs 3), not schedule.  At N=2048 a 128x128 grid = 256 blocks
// = 1/CU: every barrier/vmcnt stall is fully exposed.  Fix: 128x64 tiles ->
// grid 512 = 2 blocks/CU; independent barrier domains hide each other's
// stalls (m114).  256 threads/block (4 waves 2x2, wave tile 64x32), LDS
// 48KB/block (96KB/CU), __launch_bounds__(256,2) -> 256-VGPR cap.
// K-loop keeps the r7 counted-vmcnt discipline: BK=64, 2 phases/tile
// (ph1 = A-mhalf0 x B-all, B frags held in regs; ph2 = A-mhalf1), 2-tile
// prefetch, XOR-swizzled LDS, XCD-aware mapping, fused epilogue.
//
// Units (2 x 16B loads/thread each): uA0 = A rows{0..31,64..95} (read ph1),
// uA1 = A{32..63,96..127} (read ph2), uB = B rows 0..63 (read ph1 only).
// Stage slots tile T: uA1(T+1)@T.ph1 -> other buf (prev occupant last read
// T-1.ph2, certified by its closing barrier); {uA0,uB}(T+2)@T.ph2 ->
// current buf (last read T.ph1, certified by ph1's closing barrier; ph2
// reads only the disjoint uA1 region).  End-of-tile wait: outstanding =
// 4 (uA0,uB T+1 from T-1.ph2) + 2 (uA1 T+1 from T.ph1) + 4 (uA0,uB T+2
// from T.ph2) = 10 -> vmcnt(4) retires exactly T+1's 6 loads.  vmcnt is
// per-wave: every buffer read sits after {each wave's own wait} -> barrier.
// LDS: 2 x 24 KB buffers = 48 KB.
// ---------------------------------------------------------------------------
#define BARRIER asm volatile("s_barrier" ::: "memory")
#define LG0     asm volatile("s_waitcnt lgkmcnt(0)" ::: "memory")
#define W4      asm volatile("s_waitcnt vmcnt(4)" ::: "memory")
#define W0      asm volatile("s_waitcnt vmcnt(0)" ::: "memory")
#define NOST    ((void)0)

// One staging unit: 2 x 16B global_load_lds.  gd/ld = global/LDS deltas
// between the unit's two row groups ((row&7) invariant under both).
#define STAGE_U(u, dst, gd, ld)                                               \
    do {                                                                      \
        __builtin_amdgcn_global_load_lds(                                     \
            (const __attribute__((address_space(1))) void*)gsrc[u],           \
            (__attribute__((address_space(3))) void*)(uintptr_t)((dst) + loff[u]), \
            16, 0, 0);                                                        \
        __builtin_amdgcn_global_load_lds(                                     \
            (const __attribute__((address_space(1))) void*)(gsrc[u] + (size_t)(gd) * NM), \
            (__attribute__((address_space(3))) void*)(uintptr_t)((dst) + loff[u] + (ld)), \
            16, 0, 0);                                                        \
        gsrc[u] += 64;                                                        \
    } while (0)

#define RD_A(BB, HOFF)                                                       \
    { _Pragma("unroll")                                                      \
      for (int r_ = 0; r_ < 2; ++r_)                                         \
        _Pragma("unroll")                                                    \
        for (int k_ = 0; k_ < 2; ++k_)                                       \
            ah[r_][k_] = *(const half8*)&(BB)[offA[r_][k_] + (HOFF)]; }

#define RD_B(BB)                                                             \
    { _Pragma("unroll")                                                      \
      for (int c_ = 0; c_ < 2; ++c_)                                         \
        _Pragma("unroll")                                                    \
        for (int k_ = 0; k_ < 2; ++k_)                                       \
            bh[c_][k_] = *(const half8*)&(BB)[offB[c_][k_]]; }

#define MPH(MH)                                                              \
    __builtin_amdgcn_s_setprio(1);                                           \
    _Pragma("unroll")                                                        \
    for (int r_ = 0; r_ < 2; ++r_)                                           \
        _Pragma("unroll")                                                    \
        for (int c_ = 0; c_ < 2; ++c_)                                       \
            _Pragma("unroll")                                                 \
            for (int k_ = 0; k_ < 2; ++k_)                                   \
                acc[MH][r_][c_] = __builtin_amdgcn_mfma_f32_16x16x32_f16(    \
                    ah[r_][k_], bh[c_][k_], acc[MH][r_][c_], 0, 0, 0);       \
    __builtin_amdgcn_s_setprio(0);

// One K-tile (2 phases).  S1 = stage uA1(T+1)->other; S2 = stage
// uA0,uB(T+2)->current; WEND certifies the next tile's buffer.
#define TILE2(CUR, S1, S2, WEND)                                             \
    {                                                                        \
        const f16* Bb = (CUR);                                               \
        /* ph1: A-mhalf0 x B-all */                                          \
        RD_A(Bb, 0); RD_B(Bb);                                               \
        S1;                                                                  \
        BARRIER; LG0;                                                        \
        MPH(0);                                                              \
        BARRIER;                                                             \
        /* ph2: A-mhalf1 (bh still live in regs) */                          \
        RD_A(Bb, 2048);                                                      \
        S2;                                                                  \
        BARRIER; LG0;                                                        \
        MPH(1);                                                              \
        WEND; BARRIER;                                                       \
    }

// MODE 0: A=BT=X; P = X*X^T = -X2.  Epilogue: X2 = -P (f16),
//         CT = 256*C^T = 256*(X2/24 - X/6) (f16).
// MODE 1: A=X2, BT=CT; P = 256*X2*C.  Epilogue: OUT = I + X + X2/2 + P/256.
template <int MODE>
__global__ __launch_bounds__(256, 2) void gemm_fused_kernel(
    const f16* __restrict__ Ap, const f16* __restrict__ BTp,
    const f16* __restrict__ Xp, f16* __restrict__ X2p,
    f16* __restrict__ CTp, float* __restrict__ OUT)
{
    extern __shared__ __align__(16) f16 lds[];
    constexpr int PLB  = 8192;    // B plane base (halfs): A = 128x64 halfs
    constexpr int BUFH = 12288;   // halfs per K-tile buffer (24 KB)

    const int tid  = threadIdx.x;
    const int wave = tid >> 6, lane = tid & 63;
    const int wr = wave >> 1, wc = wave & 1;   // 2 x 2 waves, wave tile 64x32
    const int l15 = lane & 15, qq = lane >> 4;

    // XCD-aware mapping: 16x32 tiles; each XCD gets an 8x8 rectangle.
    const int bid = blockIdx.x;
    const int xcd = bid & 7, li = bid >> 3;            // 64 blocks/XCD
    const int trow = (xcd & 1) * 8 + (li >> 3);        // 0..15
    const int tcol = (xcd >> 1) * 8 + (li & 7);        // 0..31
    const int rowBase = trow * 128, colBase = tcol * 64;

    // Staging: row m-group, physical chunk sp holds logical k-chunk
    // sp ^ (row&7).  m = tid>>3 in [0,32), sp = tid&7.
    const f16* gsrc[3];
    int loff[3];
    {
        const int m = tid >> 3, sp = tid & 7;
        // uA0: rows m, 64+m; uA1: rows 32+m, 96+m; uB: rows m, 32+m.
        gsrc[0] = Ap  + (size_t)(rowBase + m) * NM      + (sp ^ (m & 7)) * 8;
        gsrc[1] = Ap  + (size_t)(rowBase + 32 + m) * NM + (sp ^ (m & 7)) * 8;
        gsrc[2] = BTp + (size_t)(colBase + m) * NM      + (sp ^ (m & 7)) * 8;
        loff[0] = (m * 8 + sp) * 8;
        loff[1] = ((32 + m) * 8 + sp) * 8;
        loff[2] = PLB + (m * 8 + sp) * 8;
    }

    // Fragment LDS offsets.  A (mh=0): row = wr*64 + r*16 + l15; mh=1 adds
    // 32 rows = +2048 halfs ((row&7) invariant).  B: row = wc*32 + c*16+l15.
    int offA[2][2], offB[2][2];
    #pragma unroll
    for (int r = 0; r < 2; ++r)
        #pragma unroll
        for (int kk = 0; kk < 2; ++kk) {
            const int row = wr * 64 + r * 16 + l15;
            offA[r][kk] = (row * 8 + ((kk * 4 + qq) ^ (row & 7))) * 8;
        }
    #pragma unroll
    for (int c = 0; c < 2; ++c)
        #pragma unroll
        for (int kk = 0; kk < 2; ++kk) {
            const int row = wc * 32 + c * 16 + l15;
            offB[c][kk] = PLB + (row * 8 + ((kk * 4 + qq) ^ (row & 7))) * 8;
        }

    float4v acc[2][2][2];
    #pragma unroll
    for (int mh = 0; mh < 2; ++mh)
        #pragma unroll
        for (int r = 0; r < 2; ++r)
            #pragma unroll
            for (int c = 0; c < 2; ++c)
                acc[mh][r][c] = (float4v){0.f, 0.f, 0.f, 0.f};

    half8 ah[2][2], bh[2][2];

    f16* B0 = lds;
    f16* B1 = lds + BUFH;

    // Prologue: tile0 all 3 units (6 loads) + uA0,uB(t1) (4 loads);
    // own-wave vmcnt(4) retires tile-0's 6; barrier certifies block-wide.
    STAGE_U(0, B0, 64, 4096); STAGE_U(1, B0, 64, 4096); STAGE_U(2, B0, 32, 2048);
    STAGE_U(0, B1, 64, 4096); STAGE_U(2, B1, 32, 2048);
    W4; BARRIER;

    // Tiles 0..29 in pairs (15 iterations).
    #pragma unroll 1
    for (int i = 0; i < 15; ++i) {
        TILE2(B0, STAGE_U(1, B1, 64, 4096),
              { STAGE_U(0, B0, 64, 4096); STAGE_U(2, B0, 32, 2048); }, W4)
        TILE2(B1, STAGE_U(1, B0, 64, 4096),
              { STAGE_U(0, B1, 64, 4096); STAGE_U(2, B1, 32, 2048); }, W4)
    }
    // Tail: tile 30 stages only uA1(31) and drains (6 outstanding -> W0);
    // tile 31 stages nothing.
    TILE2(B0, STAGE_U(1, B1, 64, 4096), NOST, W0)
    TILE2(B1, NOST, NOST, NOST)

    // Fused epilogue.  C/D layout: col = lane&15, row = qq*4 + g.
    #pragma unroll
    for (int mh = 0; mh < 2; ++mh)
        #pragma unroll
        for (int r = 0; r < 2; ++r)
            #pragma unroll
            for (int c = 0; c < 2; ++c)
                #pragma unroll
                for (int g = 0; g < 4; ++g) {
                    const int row = rowBase + wr * 64 + mh * 32 + r * 16 + qq * 4 + g;
                    const int col = colBase + wc * 32 + c * 16 + l15;
                    const size_t off = (size_t)row * NM + col;
                    const float p = acc[mh][r][c][g];
                    if (MODE == 0) {
                        const float v = -p;               // X2 = -(X*X^T)
                        const float x = (float)Xp[off];
                        X2p[off] = (f16)v;
                        CTp[off] = (f16)(v * (256.0f / 24.0f) - x * (256.0f / 6.0f));
                    } else {
                        const float x  = (float)Xp[off];
                        const float x2 = (float)X2p[off];
                        float o = x + 0.5f * x2 + p * (1.0f / 256.0f);
                        if (row == col) o += 1.0f;
                        OUT[off] = o;
                    }
                }
}

// ---------------------------------------------------------------------------
// exp(S) ~= T4(S) = I + X + X2/2 + X2*(X/6 + X2/24),  X = A - A^T.
// ws: X, X2, CT f16 planes = 25.2 MB.  3 dispatches.
// ---------------------------------------------------------------------------
extern "C" void kernel_launch(void* const* d_in, const int* in_sizes, int n_in,
                              void* d_out, int out_size, void* d_ws, size_t ws_size,
                              hipStream_t stream) {
    const float* A = (const float*)d_in[0];
    float* out = (float*)d_out;
    const size_t NN = (size_t)NM * NM;

    f16* X  = (f16*)d_ws;
    f16* X2 = X + NN;
    f16* CT = X2 + NN;

    static int attr_done = 0;
    if (!attr_done) {
        hipFuncSetAttribute((const void*)gemm_fused_kernel<0>,
                            hipFuncAttributeMaxDynamicSharedMemorySize, 49152);
        hipFuncSetAttribute((const void*)gemm_fused_kernel<1>,
                            hipFuncAttributeMaxDynamicSharedMemorySize, 49152);
        attr_done = 1;
    }

    dim3 tb(32, 8), tg(NM / 32, NM / 32);
    // 1) X = A - A^T
    skew_f16_kernel<<<tg, tb, 0, stream>>>(A, X);
    // 2) X2 = X*X (via -X*X^T), fused CT = 256*(X2/24 - X/6)
    gemm_fused_kernel<0><<<512, 256, 49152, stream>>>(X, X, X, X2, CT, nullptr);
    // 3) OUT = I + X + X2/2 + (X2*CT^T)/256
    gemm_fused_kernel<1><<<512, 256, 49152, stream>>>(X2, CT, X, X2, nullptr, out);
}

// Round 9
// 112.498 us; speedup vs baseline: 3.1303x; 1.0560x over previous
//
#include <hip/hip_runtime.h>
#include <stdint.h>

#define NM 2048

typedef _Float16 f16;
typedef unsigned char u8;
typedef __attribute__((ext_vector_type(4))) float float4v;

// float -> OCP e4m3 byte (RNE, hardware convert; gfx950 = OCP format)
__device__ inline u8 to_fp8(float v) {
    return (u8)(__builtin_amdgcn_cvt_pk_fp8_f32(v, v, 0, false) & 0xff);
}

// ---------------------------------------------------------------------------
// X = A - A^T: f16 master plane + fp8 operand plane Xq = fp8(32*X).
// (raw X entries ~0.014 sd are SUBNORMAL in e4m3 -> scale into normal range)
// ---------------------------------------------------------------------------
__global__ void skew_f16_kernel(const float* __restrict__ A, f16* __restrict__ X,
                                u8* __restrict__ Xq) {
    __shared__ float t[32][33];
    const int bx = blockIdx.x * 32, by = blockIdx.y * 32;
    const int tx = threadIdx.x, ty = threadIdx.y;
    #pragma unroll
    for (int r = 0; r < 32; r += 8)
        t[ty + r][tx] = A[(size_t)(bx + ty + r) * NM + by + tx];
    __syncthreads();
    #pragma unroll
    for (int r = 0; r < 32; r += 8) {
        const int i = by + ty + r, j = bx + tx;
        const float x = A[(size_t)i * NM + j] - t[tx][ty + r];
        X[(size_t)i * NM + j]  = (f16)x;
        Xq[(size_t)i * NM + j] = to_fp8(32.0f * x);
    }
}

// ---------------------------------------------------------------------------
// Round-9: fp8 operands + BK=128.  r8's counters say all-pipes-idle at
// ~3750cyc/K-tile; two suspects: operand-byte path (AI=43 FLOP/B at 128x64)
// and latency/sync amortization (32 tiles, 2-tile prefetch).  fp8 halves
// staged bytes (AI 2x) and BK=128 halves tile count (sync/2, prefetch
// distance in cycles 2x) at unchanged LDS (24KB/buf) and 2 blocks/CU.
// MFMA: mfma_f32_16x16x32_fp8_fp8 (same rate as f16 - this is a BYTES play).
// Schedule = r8's proven choreography verbatim (units/slots/vmcnt(4)).
//
// Scales: A0=B0=Xq=32X -> acc0 = 1024*(X*X^T) = -1024*X2.
//         A1=X2q=64*X2, B1=CTq=256*C^T -> acc1 = 16384*(X2*C).
// LDS buffer: A 128x128B=16KB + B 64x128B=8KB = 24KB; 2 bufs = 48KB/block.
// Units (2 x 16B loads/thread): uA0=A rows{0..31,64..95} (read ph1),
// uA1=A{32..63,96..127} (ph2), uB=B rows 0..63 (ph1, frags live thru ph2).
// Slots tile T: uA1(T+1)@T.ph1 -> other buf; {uA0,uB}(T+2)@T.ph2 -> current
// buf (regions disjoint from ph2 reads; last reads certified by ph1's
// closing barrier).  End-of-tile: 10 outstanding -> vmcnt(4) retires exactly
// T+1's 6.  vmcnt is per-wave: reads only after {every wave's wait}->barrier.
// ---------------------------------------------------------------------------
#define BARRIER asm volatile("s_barrier" ::: "memory")
#define LG0     asm volatile("s_waitcnt lgkmcnt(0)" ::: "memory")
#define W4      asm volatile("s_waitcnt vmcnt(4)" ::: "memory")
#define W0      asm volatile("s_waitcnt vmcnt(0)" ::: "memory")
#define NOST    ((void)0)

// One staging unit: 2 x 16B global_load_lds; gd/ld = row/byte deltas
// between the unit's two row groups ((row&7) invariant under both).
#define STAGE_U(u, dst, gd, ld)                                               \
    do {                                                                      \
        __builtin_amdgcn_global_load_lds(                                     \
            (const __attribute__((address_space(1))) void*)gsrc[u],           \
            (__attribute__((address_space(3))) void*)(uintptr_t)((dst) + loff[u]), \
            16, 0, 0);                                                        \
        __builtin_amdgcn_global_load_lds(                                     \
            (const __attribute__((address_space(1))) void*)(gsrc[u] + (size_t)(gd) * NM), \
            (__attribute__((address_space(3))) void*)(uintptr_t)((dst) + loff[u] + (ld)), \
            16, 0, 0);                                                        \
        gsrc[u] += 128;  /* BK=128 fp8 bytes */                               \
    } while (0)

#define RD_A(BB, HOFF)                                                       \
    { _Pragma("unroll")                                                      \
      for (int r_ = 0; r_ < 2; ++r_)                                         \
        _Pragma("unroll")                                                    \
        for (int k_ = 0; k_ < 4; ++k_)                                       \
            ah[r_][k_] = *(const long*)((BB) + offA[r_][k_] + (HOFF)); }

#define RD_B(BB)                                                             \
    { _Pragma("unroll")                                                      \
      for (int c_ = 0; c_ < 2; ++c_)                                         \
        _Pragma("unroll")                                                    \
        for (int k_ = 0; k_ < 4; ++k_)                                       \
            bh[c_][k_] = *(const long*)((BB) + offB[c_][k_]); }

#define MPH(MH)                                                              \
    __builtin_amdgcn_s_setprio(1);                                           \
    _Pragma("unroll")                                                        \
    for (int r_ = 0; r_ < 2; ++r_)                                           \
        _Pragma("unroll")                                                    \
        for (int c_ = 0; c_ < 2; ++c_)                                       \
            _Pragma("unroll")                                                 \
            for (int k_ = 0; k_ < 4; ++k_)                                   \
                acc[MH][r_][c_] = __builtin_amdgcn_mfma_f32_16x16x32_fp8_fp8(\
                    ah[r_][k_], bh[c_][k_], acc[MH][r_][c_], 0, 0, 0);       \
    __builtin_amdgcn_s_setprio(0);

#define TILE2(CUR, S1, S2, WEND)                                             \
    {                                                                        \
        const u8* Bb = (CUR);                                                \
        /* ph1: A-mhalf0 x B-all */                                          \
        RD_A(Bb, 0); RD_B(Bb);                                               \
        S1;                                                                  \
        BARRIER; LG0;                                                        \
        MPH(0);                                                              \
        BARRIER;                                                             \
        /* ph2: A-mhalf1 (bh still live in regs) */                          \
        RD_A(Bb, 4096);                                                      \
        S2;                                                                  \
        BARRIER; LG0;                                                        \
        MPH(1);                                                              \
        WEND; BARRIER;                                                       \
    }

// MODE 0: acc = -1024*X2.  Epilogue: X2f = f16(X2), X2q = fp8(64*X2),
//         CTq = fp8(256*(X2/24 - X/6)).
// MODE 1: acc = 16384*(X2*C).  Epilogue: OUT = I + X + X2/2 + acc/16384.
template <int MODE>
__global__ __launch_bounds__(256, 2) void gemm_fused_kernel(
    const u8* __restrict__ Ap, const u8* __restrict__ BTp,
    const f16* __restrict__ Xf, f16* __restrict__ X2f,
    u8* __restrict__ X2q, u8* __restrict__ CTq, float* __restrict__ OUT)
{
    extern __shared__ __align__(16) u8 lds[];
    constexpr int PLBB = 16384;   // B plane base (bytes): A plane = 16 KB
    constexpr int BUFB = 24576;   // bytes per K-tile buffer (24 KB)

    const int tid  = threadIdx.x;
    const int wave = tid >> 6, lane = tid & 63;
    const int wr = wave >> 1, wc = wave & 1;   // 2 x 2 waves, wave tile 64x32
    const int l15 = lane & 15, qq = lane >> 4;

    // XCD-aware mapping: 16x32 tiles; each XCD gets an 8x8 rectangle.
    const int bid = blockIdx.x;
    const int xcd = bid & 7, li = bid >> 3;            // 64 blocks/XCD
    const int trow = (xcd & 1) * 8 + (li >> 3);        // 0..15
    const int tcol = (xcd >> 1) * 8 + (li & 7);        // 0..31
    const int rowBase = trow * 128, colBase = tcol * 64;

    // Staging: row r, physical 16B chunk sp holds logical chunk sp ^ (r&7).
    const u8* gsrc[3];
    int loff[3];
    {
        const int m = tid >> 3, sp = tid & 7;          // m in [0,32)
        // uA0: rows m, m+64; uA1: rows 32+m, 96+m; uB: rows m, m+32.
        gsrc[0] = Ap  + (size_t)(rowBase + m) * NM      + (sp ^ (m & 7)) * 16;
        gsrc[1] = Ap  + (size_t)(rowBase + 32 + m) * NM + (sp ^ (m & 7)) * 16;
        gsrc[2] = BTp + (size_t)(colBase + m) * NM      + (sp ^ (m & 7)) * 16;
        loff[0] = m * 128 + sp * 16;
        loff[1] = (32 + m) * 128 + sp * 16;
        loff[2] = PLBB + m * 128 + sp * 16;
    }

    // Fragment offsets (bytes).  Lane needs A[row][kk*32 + qq*8 ..+8):
    // 16B chunk = 2*kk + (qq>>1) (XOR-swizzled by row&7), 8B half = qq&1.
    // mh1 = +32 rows = +4096 bytes ((row&7) invariant).
    int offA[2][4], offB[2][4];
    #pragma unroll
    for (int r = 0; r < 2; ++r)
        #pragma unroll
        for (int kk = 0; kk < 4; ++kk) {
            const int row = wr * 64 + r * 16 + l15;
            const int ch  = (2 * kk + (qq >> 1)) ^ (row & 7);
            offA[r][kk] = row * 128 + ch * 16 + (qq & 1) * 8;
        }
    #pragma unroll
    for (int c = 0; c < 2; ++c)
        #pragma unroll
        for (int kk = 0; kk < 4; ++kk) {
            const int row = wc * 32 + c * 16 + l15;
            const int ch  = (2 * kk + (qq >> 1)) ^ (row & 7);
            offB[c][kk] = PLBB + row * 128 + ch * 16 + (qq & 1) * 8;
        }

    float4v acc[2][2][2];
    #pragma unroll
    for (int mh = 0; mh < 2; ++mh)
        #pragma unroll
        for (int r = 0; r < 2; ++r)
            #pragma unroll
            for (int c = 0; c < 2; ++c)
                acc[mh][r][c] = (float4v){0.f, 0.f, 0.f, 0.f};

    long ah[2][4], bh[2][4];

    u8* B0 = lds;
    u8* B1 = lds + BUFB;

    // Prologue: tile0 all 3 units (6 loads) + uA0,uB(t1) (4 loads);
    // own-wave vmcnt(4) retires tile-0's 6; barrier certifies block-wide.
    STAGE_U(0, B0, 64, 8192); STAGE_U(1, B0, 64, 8192); STAGE_U(2, B0, 32, 4096);
    STAGE_U(0, B1, 64, 8192); STAGE_U(2, B1, 32, 4096);
    W4; BARRIER;

    // Tiles 0..13 in pairs (7 iterations); 16 K-tiles total (K=2048, BK=128).
    #pragma unroll 1
    for (int i = 0; i < 7; ++i) {
        TILE2(B0, STAGE_U(1, B1, 64, 8192),
              { STAGE_U(0, B0, 64, 8192); STAGE_U(2, B0, 32, 4096); }, W4)
        TILE2(B1, STAGE_U(1, B0, 64, 8192),
              { STAGE_U(0, B1, 64, 8192); STAGE_U(2, B1, 32, 4096); }, W4)
    }
    // Tail: tile 14 stages only uA1(15) and drains; tile 15 stages nothing.
    TILE2(B0, STAGE_U(1, B1, 64, 8192), NOST, W0)
    TILE2(B1, NOST, NOST, NOST)

    // Fused epilogue.  C/D layout: col = lane&15, row = qq*4 + g.
    #pragma unroll
    for (int mh = 0; mh < 2; ++mh)
        #pragma unroll
        for (int r = 0; r < 2; ++r)
            #pragma unroll
            for (int c = 0; c < 2; ++c)
                #pragma unroll
                for (int g = 0; g < 4; ++g) {
                    const int row = rowBase + wr * 64 + mh * 32 + r * 16 + qq * 4 + g;
                    const int col = colBase + wc * 32 + c * 16 + l15;
                    const size_t off = (size_t)row * NM + col;
                    const float p = acc[mh][r][c][g];
                    if (MODE == 0) {
                        const float x2 = -p * (1.0f / 1024.0f);
                        const float x  = (float)Xf[off];
                        X2f[off] = (f16)x2;
                        X2q[off] = to_fp8(64.0f * x2);
                        CTq[off] = to_fp8(x2 * (256.0f / 24.0f) - x * (256.0f / 6.0f));
                    } else {
                        const float x  = (float)Xf[off];
                        const float x2 = (float)X2f[off];
                        float o = x + 0.5f * x2 + p * (1.0f / 16384.0f);
                        if (row == col) o += 1.0f;
                        OUT[off] = o;
                    }
                }
}

// ---------------------------------------------------------------------------
// exp(S) ~= T4(S) = I + X + X2/2 + X2*(X/6 + X2/24),  X = A - A^T.
// ws: X,X2 f16 (16.8MB) + Xq,X2q,CTq fp8 (12.6MB).  3 dispatches.
// ---------------------------------------------------------------------------
extern "C" void kernel_launch(void* const* d_in, const int* in_sizes, int n_in,
                              void* d_out, int out_size, void* d_ws, size_t ws_size,
                              hipStream_t stream) {
    const float* A = (const float*)d_in[0];
    float* out = (float*)d_out;
    const size_t NN = (size_t)NM * NM;

    f16* X   = (f16*)d_ws;
    f16* X2  = X + NN;
    u8*  Xq  = (u8*)(X2 + NN);
    u8*  X2q = Xq + NN;
    u8*  CTq = X2q + NN;

    static int attr_done = 0;
    if (!attr_done) {
        hipFuncSetAttribute((const void*)gemm_fused_kernel<0>,
                            hipFuncAttributeMaxDynamicSharedMemorySize, 49152);
        hipFuncSetAttribute((const void*)gemm_fused_kernel<1>,
                            hipFuncAttributeMaxDynamicSharedMemorySize, 49152);
        attr_done = 1;
    }

    dim3 tb(32, 8), tg(NM / 32, NM / 32);
    // 1) X = A - A^T (f16 + fp8(32X))
    skew_f16_kernel<<<tg, tb, 0, stream>>>(A, X, Xq);
    // 2) X2 (f16 + fp8(64X2)) and CTq = fp8(256*C^T)
    gemm_fused_kernel<0><<<512, 256, 49152, stream>>>(Xq, Xq, X, X2, X2q, CTq, nullptr);
    // 3) OUT = I + X + X2/2 + (X2*C)
    gemm_fused_kernel<1><<<512, 256, 49152, stream>>>(X2q, CTq, X, X2, nullptr, nullptr, out);
}

// Round 12
// 109.942 us; speedup vs baseline: 3.2030x; 1.0233x over previous
//
#include <hip/hip_runtime.h>
#include <stdint.h>

#define NM 2048

typedef _Float16 f16;
typedef unsigned char u8;
typedef __attribute__((ext_vector_type(4))) float float4v;

// float -> OCP e4m3 byte (RNE, hardware convert; gfx950 = OCP format)
__device__ inline u8 to_fp8(float v) {
    return (u8)(__builtin_amdgcn_cvt_pk_fp8_f32(v, v, 0, false) & 0xff);
}

// ---------------------------------------------------------------------------
// X = A - A^T: f16 master plane + fp8 operand plane Xq = fp8(32*X).
// ---------------------------------------------------------------------------
__global__ void skew_f16_kernel(const float* __restrict__ A, f16* __restrict__ X,
                                u8* __restrict__ Xq) {
    __shared__ float t[32][33];
    const int bx = blockIdx.x * 32, by = blockIdx.y * 32;
    const int tx = threadIdx.x, ty = threadIdx.y;
    #pragma unroll
    for (int r = 0; r < 32; r += 8)
        t[ty + r][tx] = A[(size_t)(bx + ty + r) * NM + by + tx];
    __syncthreads();
    #pragma unroll
    for (int r = 0; r < 32; r += 8) {
        const int i = by + ty + r, j = bx + tx;
        const float x = A[(size_t)i * NM + j] - t[tx][ty + r];
        X[(size_t)i * NM + j]  = (f16)x;
        Xq[(size_t)i * NM + j] = to_fp8(32.0f * x);
    }
}

// ---------------------------------------------------------------------------
// Round-12 = Round-10's occupancy experiment, de-risked: STATIC __shared__
// (32 KB) replaces dynamic LDS + hipFuncSetAttribute (the only host-API
// difference vs the known-good r9 launch path; two container failures on
// r10/r11 demand removing it).  Measured hypothesis unchanged:
// MAX TLP.  Evidence r0-r9: schedule changes ~0, fp8+BK128 -6us, 1->2
// blocks/CU -4us; m102 shape curve (same kernel 320->833 TF as co-residency
// 1->3-4 blocks/CU) says occupancy is THE lever at N=2048.
// 64x64 tiles -> grid 1024 = 4 blocks/CU (32KB LDS/block -> capacity 5),
// 4 waves/block (wave tile 32x32), 16 waves/CU.  K-loop = m97-proven
// 1-phase form: {stage T+1 -> other buf; read T; 16 MFMA; LG0; W0; BAR}.
// vmcnt(0)/tile is deliberate: counted-vmcnt bought nothing at low
// occupancy (r6/r8/r9); co-resident blocks hide the drain (m114/m97).
//
// Hazards: STAGE@T -> other buf, whose last reads (tile T-1) were certified
// by T-1's LG0+BARRIER (LG0 = own-wave ds_reads complete, barrier makes it
// block-wide).  RD@T reads cur buf staged at T-1, certified by T-1's
// W0+BARRIER (W0 per-wave, barrier block-wide).  BK=128 fp8: 16 b64
// ds_reads + 16 MFMA per wave per tile; 4 global_load_lds per thread.
// ---------------------------------------------------------------------------
#define BARRIER asm volatile("s_barrier" ::: "memory")
#define LG0     asm volatile("s_waitcnt lgkmcnt(0)" ::: "memory")
#define W0      asm volatile("s_waitcnt vmcnt(0)" ::: "memory")
#define NOST    ((void)0)

#define GLL(src, dstoff)                                                      \
    __builtin_amdgcn_global_load_lds(                                         \
        (const __attribute__((address_space(1))) void*)(src),                 \
        (__attribute__((address_space(3))) void*)(uintptr_t)(dstoff),         \
        16, 0, 0)

// Stage one full K-tile (A 64x128B + B 64x128B) into dst; 4 loads/thread.
// Row +32 keeps (row&7) -> same swizzle, LDS delta 32*128 = 4096 B.
#define STAGE(dst)                                                            \
    do {                                                                      \
        GLL(gA,                (dst) + loffA);                                \
        GLL(gA + 32 * NM,      (dst) + loffA + 4096);                         \
        GLL(gB,                (dst) + loffB);                                \
        GLL(gB + 32 * NM,      (dst) + loffB + 4096);                         \
        gA += 128; gB += 128;                                                 \
    } while (0)

#define RD_ALL(BB)                                                           \
    { _Pragma("unroll")                                                      \
      for (int r_ = 0; r_ < 2; ++r_)                                         \
        _Pragma("unroll")                                                    \
        for (int k_ = 0; k_ < 4; ++k_)                                       \
            ah[r_][k_] = *(const long*)((BB) + offA[r_][k_]);                \
      _Pragma("unroll")                                                      \
      for (int c_ = 0; c_ < 2; ++c_)                                         \
        _Pragma("unroll")                                                    \
        for (int k_ = 0; k_ < 4; ++k_)                                       \
            bh[c_][k_] = *(const long*)((BB) + offB[c_][k_]); }

#define MFMA16                                                               \
    __builtin_amdgcn_s_setprio(1);                                           \
    _Pragma("unroll")                                                        \
    for (int r_ = 0; r_ < 2; ++r_)                                           \
        _Pragma("unroll")                                                    \
        for (int c_ = 0; c_ < 2; ++c_)                                       \
            _Pragma("unroll")                                                 \
            for (int k_ = 0; k_ < 4; ++k_)                                   \
                acc[r_][c_] = __builtin_amdgcn_mfma_f32_16x16x32_fp8_fp8(    \
                    ah[r_][k_], bh[c_][k_], acc[r_][c_], 0, 0, 0);           \
    __builtin_amdgcn_s_setprio(0);

// One K-tile.  SSTAGE stages the next tile (or NOST); WEND drains it for
// the next tile's reads (or NOST on the last tile).
#define TILE(CUR, SSTAGE, WEND)                                              \
    {                                                                        \
        const u8* Bb = (CUR);                                                \
        SSTAGE;                                                              \
        RD_ALL(Bb);                                                          \
        MFMA16;                                                              \
        LG0; WEND; BARRIER;                                                  \
    }

// MODE 0: A=B=Xq(=32X) -> acc = 1024*(X*X^T) = -1024*X2.
//   Epilogue: X2f=f16(X2), X2q=fp8(64*X2), CTq=fp8(256*(X2/24 - X/6)).
// MODE 1: A=X2q(=64X2), B=CTq(=256C^T) -> acc = 16384*(X2*C).
//   Epilogue: OUT = I + X + X2/2 + acc/16384.
template <int MODE>
__global__ __launch_bounds__(256, 4) void gemm_fused_kernel(
    const u8* __restrict__ Ap, const u8* __restrict__ BTp,
    const f16* __restrict__ Xf, f16* __restrict__ X2f,
    u8* __restrict__ X2q, u8* __restrict__ CTq, float* __restrict__ OUT)
{
    __shared__ __align__(16) u8 lds[32768];   // 2 x 16 KB K-tile buffers
    constexpr int PLBB = 8192;    // B plane base (bytes): A plane = 8 KB
    constexpr int BUFB = 16384;   // bytes per K-tile buffer (16 KB)

    const int tid  = threadIdx.x;
    const int wave = tid >> 6, lane = tid & 63;
    const int wr = wave >> 1, wc = wave & 1;   // 2 x 2 waves, wave tile 32x32
    const int l15 = lane & 15, qq = lane >> 4;

    // XCD mapping: 32x32 tiles; each XCD gets an 8x16 rectangle
    // (A band 512 rows = 1 MB + B band 1024 rows = 2 MB -> 3 MB < 4 MB L2).
    const int bid = blockIdx.x;
    const int xcd = bid & 7, li = bid >> 3;            // 128 blocks/XCD
    const int trow = (xcd & 3) * 8 + (li >> 4);        // 0..31
    const int tcol = (xcd >> 2) * 16 + (li & 15);      // 0..31
    const int rowBase = trow * 64, colBase = tcol * 64;

    // Staging: row r, physical 16B chunk sp holds logical chunk sp ^ (r&7).
    const int m = tid >> 3, sp = tid & 7;              // m in [0,32)
    const u8* gA = Ap  + (size_t)(rowBase + m) * NM + (sp ^ (m & 7)) * 16;
    const u8* gB = BTp + (size_t)(colBase + m) * NM + (sp ^ (m & 7)) * 16;
    const int loffA = m * 128 + sp * 16;
    const int loffB = PLBB + m * 128 + sp * 16;

    // Fragment offsets (bytes).  Lane reads [row][kk*32 + qq*8 ..+8):
    // 16B chunk = (2*kk + (qq>>1)) ^ (row&7), 8B half = qq&1.  (r9-verified)
    int offA[2][4], offB[2][4];
    #pragma unroll
    for (int r = 0; r < 2; ++r)
        #pragma unroll
        for (int kk = 0; kk < 4; ++kk) {
            const int row = wr * 32 + r * 16 + l15;
            const int ch  = (2 * kk + (qq >> 1)) ^ (row & 7);
            offA[r][kk] = row * 128 + ch * 16 + (qq & 1) * 8;
        }
    #pragma unroll
    for (int c = 0; c < 2; ++c)
        #pragma unroll
        for (int kk = 0; kk < 4; ++kk) {
            const int row = wc * 32 + c * 16 + l15;
            const int ch  = (2 * kk + (qq >> 1)) ^ (row & 7);
            offB[c][kk] = PLBB + row * 128 + ch * 16 + (qq & 1) * 8;
        }

    float4v acc[2][2];
    #pragma unroll
    for (int r = 0; r < 2; ++r)
        #pragma unroll
        for (int c = 0; c < 2; ++c)
            acc[r][c] = (float4v){0.f, 0.f, 0.f, 0.f};

    long ah[2][4], bh[2][4];

    u8* B0 = lds;
    u8* B1 = lds + BUFB;

    // Prologue: stage tile 0, drain, certify block-wide.
    STAGE(B0);
    W0; BARRIER;

    // 16 K-tiles (K=2048, BK=128) in pairs; last tile peeled (no stage).
    #pragma unroll 1
    for (int i = 0; i < 7; ++i) {
        TILE(B0, STAGE(B1), W0)
        TILE(B1, STAGE(B0), W0)
    }
    TILE(B0, STAGE(B1), W0)
    TILE(B1, NOST, NOST)

    // Fused epilogue.  C/D layout: col = lane&15, row = qq*4 + g.
    #pragma unroll
    for (int r = 0; r < 2; ++r)
        #pragma unroll
        for (int c = 0; c < 2; ++c)
            #pragma unroll
            for (int g = 0; g < 4; ++g) {
                const int row = rowBase + wr * 32 + r * 16 + qq * 4 + g;
                const int col = colBase + wc * 32 + c * 16 + l15;
                const size_t off = (size_t)row * NM + col;
                const float p = acc[r][c][g];
                if (MODE == 0) {
                    const float x2 = -p * (1.0f / 1024.0f);
                    const float x  = (float)Xf[off];
                    X2f[off] = (f16)x2;
                    X2q[off] = to_fp8(64.0f * x2);
                    CTq[off] = to_fp8(x2 * (256.0f / 24.0f) - x * (256.0f / 6.0f));
                } else {
                    const float x  = (float)Xf[off];
                    const float x2 = (float)X2f[off];
                    float o = x + 0.5f * x2 + p * (1.0f / 16384.0f);
                    if (row == col) o += 1.0f;
                    OUT[off] = o;
                }
            }
}

// ---------------------------------------------------------------------------
// exp(S) ~= T4(S) = I + X + X2/2 + X2*(X/6 + X2/24),  X = A - A^T.
// ws: X,X2 f16 (16.8MB) + Xq,X2q,CTq fp8 (12.6MB).  3 dispatches.
// ---------------------------------------------------------------------------
extern "C" void kernel_launch(void* const* d_in, const int* in_sizes, int n_in,
                              void* d_out, int out_size, void* d_ws, size_t ws_size,
                              hipStream_t stream) {
    const float* A = (const float*)d_in[0];
    float* out = (float*)d_out;
    const size_t NN = (size_t)NM * NM;

    f16* X   = (f16*)d_ws;
    f16* X2  = X + NN;
    u8*  Xq  = (u8*)(X2 + NN);
    u8*  X2q = Xq + NN;
    u8*  CTq = X2q + NN;

    dim3 tb(32, 8), tg(NM / 32, NM / 32);
    // 1) X = A - A^T (f16 + fp8(32X))
    skew_f16_kernel<<<tg, tb, 0, stream>>>(A, X, Xq);
    // 2) X2 (f16 + fp8(64X2)) and CTq = fp8(256*C^T)
    gemm_fused_kernel<0><<<1024, 256, 0, stream>>>(Xq, Xq, X, X2, X2q, CTq, nullptr);
    // 3) OUT = I + X + X2/2 + (X2*C)
    gemm_fused_kernel<1><<<1024, 256, 0, stream>>>(X2q, CTq, X, X2, nullptr, nullptr, out);
}